// Round 6
// baseline (566.776 us; speedup 1.0000x reference)
//
#include <hip/hip_runtime.h>
#include <stdint.h>

#define NNODES 20000
#define NEDGES 400000
#define MTILES 1250   // 20000/16
#define KS1 68        // layer-1 msg GEMM ksteps: 64 (T@V1) + 4 (zi@Ws1)

typedef __attribute__((ext_vector_type(8))) short short8;
typedef __attribute__((ext_vector_type(4))) float floatx4;

__device__ __forceinline__ float bf2f(uint16_t u){ return __uint_as_float(((uint32_t)u)<<16); }
__device__ __forceinline__ uint16_t f2bf(float f){
  uint32_t x = __float_as_uint(f);
  x += 0x7FFFu + ((x>>16)&1u);
  return (uint16_t)(x>>16);
}
__device__ __forceinline__ uint32_t packbf(float a, float b){
  return (uint32_t)f2bf(a) | ((uint32_t)f2bf(b)<<16);
}
__device__ __forceinline__ float2 bfpair(uint32_t v){
  return make_float2(__uint_as_float(v<<16), __uint_as_float(v & 0xFFFF0000u));
}
__device__ __forceinline__ float siluf(float x){ return x/(1.0f+__expf(-x)); }
__device__ __forceinline__ float ldf(const void* p, int i, int md){
  return (md==1) ? bf2f(((const uint16_t*)p)[i]) : ((const float*)p)[i];
}

// converted-weights layout (float elements within conv buffer)
#define OFF_V0   0
#define N_V0     32768
#define OFF_WS1  32768
#define N_WS1    16384
#define OFF_BS1  49152
#define N_BS1    128
#define OFF_V1   49280
#define N_V1     262144
#define OFF_WA   311424
#define N_WA     98304
#define OFF_BA   409728
#define N_BA     768
#define OFF_WB   410496
#define N_WB     98304
#define OFF_BB   508800
#define N_BB     768
#define N_CONV   509568

// ---------------- dtype probe ----------------
__global__ void k_probe(const void* dist, int* mode){
  if(threadIdx.x != 0 || blockIdx.x != 0) return;
  const float* f = (const float*)dist;
  const uint16_t* h = (const uint16_t*)dist;
  int okf = 1, okb = 1;
  for(int i=0;i<256;i++){
    float a = f[i];       okf &= (a >= 0.7f) & (a <= 5.1f);
    float b = bf2f(h[i]); okb &= (b >= 0.7f) & (b <= 5.1f);
  }
  *mode = okb ? 1 : (okf ? 0 : 1);
}

// ---------------- convert all weight tensors to fp32 ----------------
__global__ __launch_bounds__(256) void k_conv(const void* s0,const void* s1,const void* s2,const void* s3,
                                              const void* s4,const void* s5,const void* s6,const void* s7,
                                              const int* __restrict__ modep, float* __restrict__ dst){
  int md = *modep;
  int i = blockIdx.x*256 + threadIdx.x;
  if(i >= N_CONV) return;
  const void* src; int t = i;
  if(t < N_V0){src=s0;}
  else if((t-=N_V0) < N_WS1){src=s1;}
  else if((t-=N_WS1) < N_BS1){src=s2;}
  else if((t-=N_BS1) < N_V1){src=s3;}
  else if((t-=N_V1) < N_WA){src=s4;}
  else if((t-=N_WA) < N_BA){src=s5;}
  else if((t-=N_BA) < N_WB){src=s6;}
  else {t-=N_WB; src=s7;}
  dst[i] = ldf(src, t, md);
}

// ---------------- CSR build ----------------
__global__ __launch_bounds__(256) void k_hist(const int* __restrict__ src, int* __restrict__ cnt){
  int e = blockIdx.x*256 + threadIdx.x;
  if(e < NEDGES){
    int s = src[e];
    if((unsigned)s < NNODES) atomicAdd(&cnt[s], 1);
  }
}

__global__ __launch_bounds__(64) void k_scan(int* cnt_cur, int* offs){
  int t = threadIdx.x;
  const int chunk = (NNODES + 63)/64;   // 313
  int lo = t*chunk, hi = lo+chunk;
  if(lo > NNODES) lo = NNODES;
  if(hi > NNODES) hi = NNODES;
  int s = 0;
  for(int i=lo;i<hi;i++) s += cnt_cur[i];
  int v = s;
  #pragma unroll
  for(int d=1; d<64; d<<=1){
    int u = __shfl_up(v, d);
    if(t >= d) v += u;
  }
  int run = v - s;
  for(int i=lo;i<hi;i++){
    int c = cnt_cur[i];
    offs[i] = run;
    cnt_cur[i] = run;
    run += c;
  }
  if(t==63) offs[NNODES] = run;
}

__global__ __launch_bounds__(256) void k_fill(const int* __restrict__ src,
                                              const int* __restrict__ edst,
                                              const int* __restrict__ species,
                                              int* __restrict__ cur,
                                              int* __restrict__ dsts,
                                              int* __restrict__ sps,
                                              int* __restrict__ pos){
  int e = blockIdx.x*256 + threadIdx.x;
  if(e >= NEDGES) return;
  int s = src[e];
  if((unsigned)s >= NNODES) s = 0;
  int p = atomicAdd(&cur[s], 1);
  if((unsigned)p >= NEDGES) p = 0;
  pos[e] = p;
  int dn = edst[e];
  if((unsigned)dn >= NNODES) dn = 0;
  dsts[p] = dn;
  int sp = species[dn];
  if((unsigned)sp >= 51) sp = 0;
  sps[p] = sp;
}

// ---------------- radial basis -> sorted bf16 rows g_s[p][16] ----------------
__global__ __launch_bounds__(256) void k_G(const void* __restrict__ dist,
                                           const void* __restrict__ sw,
                                           const int* __restrict__ modep,
                                           const int* __restrict__ pos,
                                           uint16_t* __restrict__ gs){
  int e = blockIdx.x*256 + threadIdx.x;
  if(e >= NEDGES) return;
  int md = *modep;
  float r = ldf(dist, e, md);
  float w = ldf(sw, e, md);
  float rinv = 1.0f/r;
  const float sigma = 0.8f/15.0f;
  const float isig  = 15.0f/0.8f;
  uint32_t u[8];
  #pragma unroll
  for(int j=0;j<8;j++){
    float mu0 = 0.2f + sigma*(float)(2*j);
    float mu1 = 0.2f + sigma*(float)(2*j+1);
    float t0 = (rinv-mu0)*isig, t1 = (rinv-mu1)*isig;
    u[j] = packbf(w*__expf(-0.5f*t0*t0), w*__expf(-0.5f*t1*t1));
  }
  int p = pos[e];
  uint4* o = (uint4*)(gs + (size_t)p*16);
  o[0] = make_uint4(u[0],u[1],u[2],u[3]);
  o[1] = make_uint4(u[4],u[5],u[6],u[7]);
}

// ---------------- species tables ----------------
__global__ __launch_bounds__(128) void k_spec(const void* __restrict__ Z,
                                              const void* __restrict__ Ws0,
                                              const void* __restrict__ bs0,
                                              const int* __restrict__ modep,
                                              float* __restrict__ ZWs0,
                                              uint16_t* __restrict__ zfb){
  int s = blockIdx.x, d = threadIdx.x;
  int md = *modep;
  float zk[16];
  #pragma unroll
  for(int k=0;k<16;k++) zk[k] = ldf(Z, s*16+k, md);
  float a = ldf(bs0, d, md);
  #pragma unroll
  for(int k=0;k<16;k++) a = fmaf(zk[k], ldf(Ws0, k*128+d, md), a);
  ZWs0[s*128+d] = a;
  if(d < 16) zfb[s*16+d] = f2bf(zk[d]);
}

// ---------------- pack W (Kx128 fp32) into MFMA B-fragment layout, bf16 ----------------
__global__ __launch_bounds__(256) void k_prepB(const float* __restrict__ W, int Ksteps,
                                               uint16_t* __restrict__ Bf){
  int idx = blockIdx.x*256 + threadIdx.x;
  int total = Ksteps*8*64;
  if(idx >= total) return;
  int l = idx & 63, nt = (idx>>6)&7, kk = idx>>9;
  int kbase = kk*32 + (l>>4)*8;
  int dim = nt*16 + (l&15);
  uint32_t u[4];
  #pragma unroll
  for(int t=0;t<4;t++){
    float f0 = W[(size_t)(kbase+2*t)*128 + dim];
    float f1 = W[(size_t)(kbase+2*t+1)*128 + dim];
    u[t] = packbf(f0,f1);
  }
  ((uint4*)Bf)[idx] = make_uint4(u[0],u[1],u[2],u[3]);
}

// pack all 12 onsite 128x128 weights into frags
__global__ __launch_bounds__(256) void k_prepW(const float* __restrict__ conv,
                                               uint16_t* __restrict__ Wf){
  int idx = blockIdx.x*256 + threadIdx.x;
  if(idx >= 12*2048) return;
  int wi = idx>>11, r = idx&2047;
  int l = r & 63, nt = (r>>6)&7, kk = r>>9;
  const float* W = conv + ((wi<6) ? (OFF_WA + wi*16384) : (OFF_WB + (wi-6)*16384));
  int kbase = kk*32 + (l>>4)*8;
  int dim = nt*16 + (l&15);
  uint32_t u[4];
  #pragma unroll
  for(int t=0;t<4;t++){
    float f0 = W[(size_t)(kbase+2*t)*128 + dim];
    float f1 = W[(size_t)(kbase+2*t+1)*128 + dim];
    u[t] = packbf(f0,f1);
  }
  ((uint4*)Wf)[idx] = make_uint4(u[0],u[1],u[2],u[3]);
}

// ---------------- layer-0 fused: scatter into LDS A-frags + MFMA GEMM ----------------
// block = 4 waves = one mtile (16 nodes). LDS tile: 8 ksteps x 64 slots x 8 bf16, XOR-swizzled.
__global__ __launch_bounds__(256) void k_msg0f(const int* __restrict__ offs,
                                               const int* __restrict__ sps,
                                               const uint16_t* __restrict__ gs,
                                               const uint16_t* __restrict__ zfb,
                                               const uint16_t* __restrict__ Bf,
                                               const int* __restrict__ species,
                                               const float* __restrict__ ZWs0,
                                               float* __restrict__ zi){
  __shared__ uint16_t ldsA[8*64*8];   // 8 KB
  int w = threadIdx.x>>6, l = threadIdx.x&63;
  int n0 = blockIdx.x*16;
  int u = l&31, dup = l>>5;
  int b = u>>1, zk0 = (u&1)*8;
  // phase A: 4 nodes per wave
  for(int i=0;i<4;i++){
    int m = w*4 + i;
    int n = n0 + m;
    float acc[8];
    #pragma unroll
    for(int j=0;j<8;j++) acc[j]=0.f;
    int beg = offs[n], end = offs[n+1];
    for(int ei=beg+dup; ei<end; ei+=2){
      int sp = sps[ei];
      float g = bf2f(gs[(size_t)ei*16 + b]);
      uint4 z = *(const uint4*)(zfb + sp*16 + zk0);
      float2 f0=bfpair(z.x), f1=bfpair(z.y), f2=bfpair(z.z), f3=bfpair(z.w);
      acc[0]=fmaf(g,f0.x,acc[0]); acc[1]=fmaf(g,f0.y,acc[1]);
      acc[2]=fmaf(g,f1.x,acc[2]); acc[3]=fmaf(g,f1.y,acc[3]);
      acc[4]=fmaf(g,f2.x,acc[4]); acc[5]=fmaf(g,f2.y,acc[5]);
      acc[6]=fmaf(g,f3.x,acc[6]); acc[7]=fmaf(g,f3.y,acc[7]);
    }
    #pragma unroll
    for(int j=0;j<8;j++) acc[j] += __shfl(acc[j], l^32);
    if(dup==0){
      uint32_t p0 = packbf(acc[0],acc[1]), p1 = packbf(acc[2],acc[3]);
      uint32_t p2 = packbf(acc[4],acc[5]), p3 = packbf(acc[6],acc[7]);
      int kk = u>>2, q = u&3;
      int p = q*16 + m;
      int slot = kk*64 + (p ^ kk);
      *(uint4*)(&ldsA[slot*8]) = make_uint4(p0,p1,p2,p3);
    }
  }
  __syncthreads();
  // phase B: wave w -> ntiles w and w+4
  floatx4 acc1 = (floatx4){0.f,0.f,0.f,0.f};
  floatx4 acc2 = (floatx4){0.f,0.f,0.f,0.f};
  const short8* Bp = (const short8*)Bf;
  int nt1 = w, nt2 = w+4;
  #pragma unroll
  for(int kk=0;kk<8;kk++){
    short8 a = *(const short8*)(&ldsA[(kk*64 + (l^kk))*8]);
    short8 b1 = Bp[(size_t)(kk*8+nt1)*64 + l];
    short8 b2 = Bp[(size_t)(kk*8+nt2)*64 + l];
    acc1 = __builtin_amdgcn_mfma_f32_16x16x32_bf16(a, b1, acc1, 0,0,0);
    acc2 = __builtin_amdgcn_mfma_f32_16x16x32_bf16(a, b2, acc2, 0,0,0);
  }
  int col = l&15, quad = l>>4;
  #pragma unroll
  for(int reg=0;reg<4;reg++){
    int node = n0 + quad*4 + reg;
    int sp = species[node];
    if((unsigned)sp >= 51) sp = 0;
    int d1 = nt1*16 + col, d2 = nt2*16 + col;
    zi[(size_t)node*128 + d1] = siluf(acc1[reg] + ZWs0[sp*128 + d1]);
    zi[(size_t)node*128 + d2] = siluf(acc2[reg] + ZWs0[sp*128 + d2]);
  }
}

// ---------------- layer-1 fused: scatter into LDS A-frags + MFMA GEMM (KS1=68) ----------------
__global__ __launch_bounds__(256) void k_msg1f(const int* __restrict__ offs,
                                               const int* __restrict__ dsts,
                                               const uint16_t* __restrict__ gs,
                                               const uint16_t* __restrict__ zib,
                                               const uint16_t* __restrict__ Bf,
                                               const float* __restrict__ bias,
                                               float* __restrict__ zi){
  __shared__ uint16_t ldsA[64*64*8];   // 64 KB
  int w = threadIdx.x>>6, l = threadIdx.x&63;
  int n0 = blockIdx.x*16;
  int b = l&15, ks = l>>4;
  int kk_mine = b*4 + ks;
  // phase A: 4 nodes per wave
  for(int i=0;i<4;i++){
    int m = w*4 + i;
    int n = n0 + m;
    float acc[32];
    #pragma unroll
    for(int j=0;j<32;j++) acc[j]=0.f;
    int beg = offs[n], end = offs[n+1];
    int ei = beg;
    for(; ei+2<=end; ei+=2){
      int dn0 = dsts[ei], dn1 = dsts[ei+1];
      float g0 = bf2f(gs[(size_t)ei*16 + b]);
      float g1 = bf2f(gs[(size_t)(ei+1)*16 + b]);
      const uint4* z0p = (const uint4*)(zib + (size_t)dn0*128 + ks*32);
      const uint4* z1p = (const uint4*)(zib + (size_t)dn1*128 + ks*32);
      uint4 z0[4] = {z0p[0], z0p[1], z0p[2], z0p[3]};
      uint4 z1[4] = {z1p[0], z1p[1], z1p[2], z1p[3]};
      #pragma unroll
      for(int q=0;q<4;q++){
        float2 a0=bfpair(z0[q].x), a1=bfpair(z0[q].y), a2=bfpair(z0[q].z), a3=bfpair(z0[q].w);
        acc[q*8+0]=fmaf(g0,a0.x,acc[q*8+0]); acc[q*8+1]=fmaf(g0,a0.y,acc[q*8+1]);
        acc[q*8+2]=fmaf(g0,a1.x,acc[q*8+2]); acc[q*8+3]=fmaf(g0,a1.y,acc[q*8+3]);
        acc[q*8+4]=fmaf(g0,a2.x,acc[q*8+4]); acc[q*8+5]=fmaf(g0,a2.y,acc[q*8+5]);
        acc[q*8+6]=fmaf(g0,a3.x,acc[q*8+6]); acc[q*8+7]=fmaf(g0,a3.y,acc[q*8+7]);
        float2 b0=bfpair(z1[q].x), b1=bfpair(z1[q].y), b2=bfpair(z1[q].z), b3=bfpair(z1[q].w);
        acc[q*8+0]=fmaf(g1,b0.x,acc[q*8+0]); acc[q*8+1]=fmaf(g1,b0.y,acc[q*8+1]);
        acc[q*8+2]=fmaf(g1,b1.x,acc[q*8+2]); acc[q*8+3]=fmaf(g1,b1.y,acc[q*8+3]);
        acc[q*8+4]=fmaf(g1,b2.x,acc[q*8+4]); acc[q*8+5]=fmaf(g1,b2.y,acc[q*8+5]);
        acc[q*8+6]=fmaf(g1,b3.x,acc[q*8+6]); acc[q*8+7]=fmaf(g1,b3.y,acc[q*8+7]);
      }
    }
    if(ei < end){
      int dn0 = dsts[ei];
      float g0 = bf2f(gs[(size_t)ei*16 + b]);
      const uint4* z0p = (const uint4*)(zib + (size_t)dn0*128 + ks*32);
      #pragma unroll
      for(int q=0;q<4;q++){
        uint4 z = z0p[q];
        float2 a0=bfpair(z.x), a1=bfpair(z.y), a2=bfpair(z.z), a3=bfpair(z.w);
        acc[q*8+0]=fmaf(g0,a0.x,acc[q*8+0]); acc[q*8+1]=fmaf(g0,a0.y,acc[q*8+1]);
        acc[q*8+2]=fmaf(g0,a1.x,acc[q*8+2]); acc[q*8+3]=fmaf(g0,a1.y,acc[q*8+3]);
        acc[q*8+4]=fmaf(g0,a2.x,acc[q*8+4]); acc[q*8+5]=fmaf(g0,a2.y,acc[q*8+5]);
        acc[q*8+6]=fmaf(g0,a3.x,acc[q*8+6]); acc[q*8+7]=fmaf(g0,a3.y,acc[q*8+7]);
      }
    }
    #pragma unroll
    for(int g4=0; g4<4; g4++){
      uint32_t p0 = packbf(acc[g4*8+0],acc[g4*8+1]);
      uint32_t p1 = packbf(acc[g4*8+2],acc[g4*8+3]);
      uint32_t p2 = packbf(acc[g4*8+4],acc[g4*8+5]);
      uint32_t p3 = packbf(acc[g4*8+6],acc[g4*8+7]);
      int p = g4*16 + m;
      int slot = kk_mine*64 + (p ^ kk_mine);
      *(uint4*)(&ldsA[slot*8]) = make_uint4(p0,p1,p2,p3);
    }
  }
  __syncthreads();
  // phase B: wave w -> ntiles w and w+4; ksteps 0..63 from LDS, 64..67 from zib (zself via Ws1 frags in Bf tail)
  floatx4 acc1 = (floatx4){0.f,0.f,0.f,0.f};
  floatx4 acc2 = (floatx4){0.f,0.f,0.f,0.f};
  const short8* Bp = (const short8*)Bf;
  int nt1 = w, nt2 = w+4;
  int col = l&15, quad = l>>4;
  for(int kk=0;kk<64;kk++){
    short8 a = *(const short8*)(&ldsA[(kk*64 + (l^kk))*8]);
    short8 b1 = Bp[(size_t)(kk*8+nt1)*64 + l];
    short8 b2 = Bp[(size_t)(kk*8+nt2)*64 + l];
    acc1 = __builtin_amdgcn_mfma_f32_16x16x32_bf16(a, b1, acc1, 0,0,0);
    acc2 = __builtin_amdgcn_mfma_f32_16x16x32_bf16(a, b2, acc2, 0,0,0);
  }
  #pragma unroll
  for(int kk=64;kk<KS1;kk++){
    uint4 za = *(const uint4*)(zib + (size_t)(n0+col)*128 + (kk-64)*32 + quad*8);
    union { short8 s; uint4 u; } A; A.u = za;
    short8 b1 = Bp[(size_t)(kk*8+nt1)*64 + l];
    short8 b2 = Bp[(size_t)(kk*8+nt2)*64 + l];
    acc1 = __builtin_amdgcn_mfma_f32_16x16x32_bf16(A.s, b1, acc1, 0,0,0);
    acc2 = __builtin_amdgcn_mfma_f32_16x16x32_bf16(A.s, b2, acc2, 0,0,0);
  }
  #pragma unroll
  for(int reg=0;reg<4;reg++){
    int node = n0 + quad*4 + reg;
    int d1 = nt1*16 + col, d2 = nt2*16 + col;
    zi[(size_t)node*128 + d1] = siluf(acc1[reg] + bias[d1]);
    zi[(size_t)node*128 + d2] = siluf(acc2[reg] + bias[d2]);
  }
}

// ---------------- onsite via MFMA: 3 x (h=silu(z@Wa+ba); z+=h@Wb+bb) ----------------
__global__ __launch_bounds__(128) void k_onsite(float* __restrict__ zi,
                                                const uint16_t* __restrict__ Waf,
                                                const float* __restrict__ ba,
                                                const uint16_t* __restrict__ Wbf,
                                                const float* __restrict__ bb,
                                                void* __restrict__ outb,
                                                long off1, int st1,
                                                long off2, int st2,
                                                const int* __restrict__ modep,
                                                uint16_t* __restrict__ zib){
  __shared__ float zbuf[2][16*132];
  __shared__ float hbuf[2][16*132];
  int w = threadIdx.x>>6, l = threadIdx.x&63;
  int mtile = blockIdx.x*2 + w;
  int n0 = mtile*16;
  int md = *modep;
  float* zb = zbuf[w];
  float* hb = hbuf[w];
  #pragma unroll
  for(int i=0;i<8;i++){
    int flat = (i*64 + l)*4;
    int node = flat>>7, k = flat&127;
    *(float4*)(zb + node*132 + k) = *(const float4*)(zi + (size_t)(n0+node)*128 + k);
  }
  __syncthreads();
  int m = l&15, q = l>>4;
  for(int j=0;j<3;j++){
    const short8* Ba = (const short8*)Waf + (size_t)j*2048 + l;
    floatx4 acc[8];
    #pragma unroll
    for(int t=0;t<8;t++) acc[t] = (floatx4){0.f,0.f,0.f,0.f};
    #pragma unroll
    for(int kk=0;kk<4;kk++){
      const float* zp = zb + m*132 + kk*32 + q*8;
      float4 a0 = *(const float4*)zp, a1 = *(const float4*)(zp+4);
      union { short8 s; uint32_t u[4]; } A;
      A.u[0]=packbf(a0.x,a0.y); A.u[1]=packbf(a0.z,a0.w);
      A.u[2]=packbf(a1.x,a1.y); A.u[3]=packbf(a1.z,a1.w);
      #pragma unroll
      for(int nt=0;nt<8;nt++){
        short8 bfr = Ba[(size_t)(kk*8+nt)*64];
        acc[nt] = __builtin_amdgcn_mfma_f32_16x16x32_bf16(A.s, bfr, acc[nt], 0,0,0);
      }
    }
    #pragma unroll
    for(int nt=0;nt<8;nt++){
      int dim = nt*16 + m;
      float bv = ba[j*128+dim];
      #pragma unroll
      for(int reg=0;reg<4;reg++)
        hb[(q*4+reg)*132 + dim] = siluf(acc[nt][reg] + bv);
    }
    __syncthreads();
    const short8* Bb = (const short8*)Wbf + (size_t)j*2048 + l;
    floatx4 acc2[8];
    #pragma unroll
    for(int t=0;t<8;t++) acc2[t] = (floatx4){0.f,0.f,0.f,0.f};
    #pragma unroll
    for(int kk=0;kk<4;kk++){
      const float* hp = hb + m*132 + kk*32 + q*8;
      float4 a0 = *(const float4*)hp, a1 = *(const float4*)(hp+4);
      union { short8 s; uint32_t u[4]; } A;
      A.u[0]=packbf(a0.x,a0.y); A.u[1]=packbf(a0.z,a0.w);
      A.u[2]=packbf(a1.x,a1.y); A.u[3]=packbf(a1.z,a1.w);
      #pragma unroll
      for(int nt=0;nt<8;nt++){
        short8 bfr = Bb[(size_t)(kk*8+nt)*64];
        acc2[nt] = __builtin_amdgcn_mfma_f32_16x16x32_bf16(A.s, bfr, acc2[nt], 0,0,0);
      }
    }
    __syncthreads();
    #pragma unroll
    for(int nt=0;nt<8;nt++){
      int dim = nt*16 + m;
      float bv = bb[j*128+dim];
      #pragma unroll
      for(int reg=0;reg<4;reg++){
        int idx = (q*4+reg)*132 + dim;
        zb[idx] = zb[idx] + acc2[nt][reg] + bv;
      }
    }
    __syncthreads();
  }
  #pragma unroll
  for(int i=0;i<8;i++){
    int flat = (i*64 + l)*4;
    int node = flat>>7, k = flat&127;
    float4 v = *(float4*)(zb + node*132 + k);
    int n = n0 + node;
    *(float4*)(zi + (size_t)n*128 + k) = v;
    uint2 pv = make_uint2(packbf(v.x,v.y), packbf(v.z,v.w));
    if(zib) *(uint2*)(zib + (size_t)n*128 + k) = pv;
    if(md==1){
      uint16_t* ob = (uint16_t*)outb;
      *(uint2*)(ob + off1 + (long)n*st1 + k) = pv;
      if(off2 >= 0) *(uint2*)(ob + off2 + (long)n*st2 + k) = pv;
    } else {
      float* ob = (float*)outb;
      *(float4*)(ob + off1 + (long)n*st1 + k) = v;
      if(off2 >= 0) *(float4*)(ob + off2 + (long)n*st2 + k) = v;
    }
  }
}

extern "C" void kernel_launch(void* const* d_in, const int* in_sizes, int n_in,
                              void* d_out, int out_size, void* d_ws, size_t ws_size,
                              hipStream_t stream){
  const int* species = (const int*)d_in[0];
  const int* esrc    = (const int*)d_in[1];
  const int* edst    = (const int*)d_in[2];
  const void* dist   = d_in[3];
  const void* swit   = d_in[4];
  const void* Z      = d_in[5];
  const void* Ws0    = d_in[6];
  const void* bs0    = d_in[7];
  const void* V0     = d_in[8];
  const void* Ws1    = d_in[9];
  const void* bs1    = d_in[10];
  const void* V1     = d_in[11];
  const void* Wa     = d_in[12];
  const void* ba     = d_in[13];
  const void* Wb     = d_in[14];
  const void* bb     = d_in[15];

  char* ws = (char*)d_ws;
  size_t off = 0;
  auto alloc = [&](size_t bytes)->void*{ void* p = ws + off; off = (off + bytes + 255) & ~(size_t)255; return p; };
  int*      offs = (int*)     alloc((size_t)(NNODES+1)*4);
  int*      cur  = (int*)     alloc((size_t)NNODES*4);
  int*      pos  = (int*)     alloc((size_t)NEDGES*4);
  int*      dsts = (int*)     alloc((size_t)NEDGES*4);
  int*      sps  = (int*)     alloc((size_t)NEDGES*4);
  uint16_t* gs   = (uint16_t*)alloc((size_t)NEDGES*16*2);      // 12.8 MB
  float*    zi   = (float*)   alloc((size_t)NNODES*128*4);     // 10.24 MB
  uint16_t* zib  = (uint16_t*)alloc((size_t)NNODES*128*2);     // 5.12 MB
  float*    ZWs0 = (float*)   alloc((size_t)51*128*4);
  uint16_t* zfb  = (uint16_t*)alloc((size_t)51*16*2);
  float*    conv = (float*)   alloc((size_t)N_CONV*4);         // 2.04 MB
  uint16_t* Bf0  = (uint16_t*)alloc((size_t)8*8*64*8*2);       // 64 KB
  uint16_t* Bf1  = (uint16_t*)alloc((size_t)KS1*8*64*8*2);     // 557 KB
  uint16_t* Wfr  = (uint16_t*)alloc((size_t)12*16384*2);       // 384 KB
  int*      mode = (int*)     alloc(256);

  const int EB = (NEDGES+255)/256;
  hipMemsetAsync(cur, 0, NNODES*4, stream);
  k_probe<<<1,64,0,stream>>>(dist, mode);
  k_conv <<<(N_CONV+255)/256,256,0,stream>>>(V0, Ws1, bs1, V1, Wa, ba, Wb, bb, mode, conv);
  k_hist <<<EB,256,0,stream>>>(esrc, cur);
  k_scan <<<1,64,0,stream>>>(cur, offs);
  k_fill <<<EB,256,0,stream>>>(esrc, edst, species, cur, dsts, sps, pos);
  k_G    <<<EB,256,0,stream>>>(dist, swit, mode, pos, gs);
  k_spec <<<51,128,0,stream>>>(Z, Ws0, bs0, mode, ZWs0, zfb);
  k_prepB<<<(8*8*64+255)/256,256,0,stream>>>(conv+OFF_V0, 8,  Bf0);
  k_prepB<<<(64*8*64+255)/256,256,0,stream>>>(conv+OFF_V1, 64, Bf1);
  k_prepB<<<(4*8*64+255)/256,256,0,stream>>>(conv+OFF_WS1, 4, Bf1 + (size_t)64*8*64*8);
  k_prepW<<<(12*2048+255)/256,256,0,stream>>>(conv, Wfr);

  const long ZIS = (long)NNODES*128;
  uint16_t* WaF0 = Wfr;
  uint16_t* WaF1 = Wfr + (size_t)3*16384;
  uint16_t* WbF0 = Wfr + (size_t)6*16384;
  uint16_t* WbF1 = Wfr + (size_t)9*16384;

  // layer 0 (fused scatter+GEMM)
  k_msg0f<<<MTILES,256,0,stream>>>(offs, sps, gs, zfb, Bf0, species, ZWs0, zi);
  k_onsite<<<MTILES/2,128,0,stream>>>(zi, WaF0, conv+OFF_BA, WbF0, conv+OFF_BB,
                                      d_out, ZIS, 256, (long)-1, 0, mode, zib);

  // layer 1 (fused scatter+GEMM incl. zself via Ws1 ksteps)
  k_msg1f<<<MTILES,256,0,stream>>>(offs, dsts, gs, zib, Bf1, conv+OFF_BS1, zi);
  k_onsite<<<MTILES/2,128,0,stream>>>(zi, WaF1, conv+OFF_BA+384, WbF1, conv+OFF_BB+384,
                                      d_out, ZIS+128, 256, (long)0, 128, mode, (uint16_t*)nullptr);
}

// Round 7
// 564.113 us; speedup vs baseline: 1.0047x; 1.0047x over previous
//
#include <hip/hip_runtime.h>
#include <stdint.h>

#define NNODES 20000
#define NEDGES 400000
#define MTILES 1250   // 20000/16
#define KS1 68        // layer-1 msg GEMM ksteps: 64 (T@V1) + 4 (zi@Ws1)

typedef __attribute__((ext_vector_type(8))) short short8;
typedef __attribute__((ext_vector_type(4))) float floatx4;

__device__ __forceinline__ float bf2f(uint16_t u){ return __uint_as_float(((uint32_t)u)<<16); }
__device__ __forceinline__ uint16_t f2bf(float f){
  uint32_t x = __float_as_uint(f);
  x += 0x7FFFu + ((x>>16)&1u);
  return (uint16_t)(x>>16);
}
__device__ __forceinline__ uint32_t packbf(float a, float b){
  return (uint32_t)f2bf(a) | ((uint32_t)f2bf(b)<<16);
}
__device__ __forceinline__ float2 bfpair(uint32_t v){
  return make_float2(__uint_as_float(v<<16), __uint_as_float(v & 0xFFFF0000u));
}
__device__ __forceinline__ float siluf(float x){ return x/(1.0f+__expf(-x)); }
__device__ __forceinline__ float ldf(const void* p, int i, int md){
  return (md==1) ? bf2f(((const uint16_t*)p)[i]) : ((const float*)p)[i];
}

// converted-weights layout (float elements within conv buffer)
#define OFF_V0   0
#define N_V0     32768
#define OFF_WS1  32768
#define N_WS1    16384
#define OFF_BS1  49152
#define N_BS1    128
#define OFF_V1   49280
#define N_V1     262144
#define OFF_WA   311424
#define N_WA     98304
#define OFF_BA   409728
#define N_BA     768
#define OFF_WB   410496
#define N_WB     98304
#define OFF_BB   508800
#define N_BB     768
#define N_CONV   509568

// ---------------- dtype probe ----------------
__global__ void k_probe(const void* dist, int* mode){
  if(threadIdx.x != 0 || blockIdx.x != 0) return;
  const float* f = (const float*)dist;
  const uint16_t* h = (const uint16_t*)dist;
  int okf = 1, okb = 1;
  for(int i=0;i<256;i++){
    float a = f[i];       okf &= (a >= 0.7f) & (a <= 5.1f);
    float b = bf2f(h[i]); okb &= (b >= 0.7f) & (b <= 5.1f);
  }
  *mode = okb ? 1 : (okf ? 0 : 1);
}

// ---------------- convert all weight tensors to fp32 ----------------
__global__ __launch_bounds__(256) void k_conv(const void* s0,const void* s1,const void* s2,const void* s3,
                                              const void* s4,const void* s5,const void* s6,const void* s7,
                                              const int* __restrict__ modep, float* __restrict__ dst){
  int md = *modep;
  int i = blockIdx.x*256 + threadIdx.x;
  if(i >= N_CONV) return;
  const void* src; int t = i;
  if(t < N_V0){src=s0;}
  else if((t-=N_V0) < N_WS1){src=s1;}
  else if((t-=N_WS1) < N_BS1){src=s2;}
  else if((t-=N_BS1) < N_V1){src=s3;}
  else if((t-=N_V1) < N_WA){src=s4;}
  else if((t-=N_WA) < N_BA){src=s5;}
  else if((t-=N_BA) < N_WB){src=s6;}
  else {t-=N_WB; src=s7;}
  dst[i] = ldf(src, t, md);
}

// ---------------- CSR build ----------------
__global__ __launch_bounds__(256) void k_hist(const int* __restrict__ src, int* __restrict__ cnt){
  int e = blockIdx.x*256 + threadIdx.x;
  if(e < NEDGES){
    int s = src[e];
    if((unsigned)s < NNODES) atomicAdd(&cnt[s], 1);
  }
}

__global__ __launch_bounds__(64) void k_scan(int* cnt_cur, int* offs){
  int t = threadIdx.x;
  const int chunk = (NNODES + 63)/64;   // 313
  int lo = t*chunk, hi = lo+chunk;
  if(lo > NNODES) lo = NNODES;
  if(hi > NNODES) hi = NNODES;
  int s = 0;
  for(int i=lo;i<hi;i++) s += cnt_cur[i];
  int v = s;
  #pragma unroll
  for(int d=1; d<64; d<<=1){
    int u = __shfl_up(v, d);
    if(t >= d) v += u;
  }
  int run = v - s;
  for(int i=lo;i<hi;i++){
    int c = cnt_cur[i];
    offs[i] = run;
    cnt_cur[i] = run;
    run += c;
  }
  if(t==63) offs[NNODES] = run;
}

__global__ __launch_bounds__(256) void k_fill(const int* __restrict__ src,
                                              const int* __restrict__ edst,
                                              const int* __restrict__ species,
                                              int* __restrict__ cur,
                                              int* __restrict__ dsts,
                                              int* __restrict__ sps,
                                              int* __restrict__ pos){
  int e = blockIdx.x*256 + threadIdx.x;
  if(e >= NEDGES) return;
  int s = src[e];
  if((unsigned)s >= NNODES) s = 0;
  int p = atomicAdd(&cur[s], 1);
  if((unsigned)p >= NEDGES) p = 0;
  pos[e] = p;
  int dn = edst[e];
  if((unsigned)dn >= NNODES) dn = 0;
  dsts[p] = dn;
  int sp = species[dn];
  if((unsigned)sp >= 51) sp = 0;
  sps[p] = sp;
}

// ---------------- radial basis -> sorted bf16 rows g_s[p][16] ----------------
__global__ __launch_bounds__(256) void k_G(const void* __restrict__ dist,
                                           const void* __restrict__ sw,
                                           const int* __restrict__ modep,
                                           const int* __restrict__ pos,
                                           uint16_t* __restrict__ gs){
  int e = blockIdx.x*256 + threadIdx.x;
  if(e >= NEDGES) return;
  int md = *modep;
  float r = ldf(dist, e, md);
  float w = ldf(sw, e, md);
  float rinv = 1.0f/r;
  const float sigma = 0.8f/15.0f;
  const float isig  = 15.0f/0.8f;
  uint32_t u[8];
  #pragma unroll
  for(int j=0;j<8;j++){
    float mu0 = 0.2f + sigma*(float)(2*j);
    float mu1 = 0.2f + sigma*(float)(2*j+1);
    float t0 = (rinv-mu0)*isig, t1 = (rinv-mu1)*isig;
    u[j] = packbf(w*__expf(-0.5f*t0*t0), w*__expf(-0.5f*t1*t1));
  }
  int p = pos[e];
  uint4* o = (uint4*)(gs + (size_t)p*16);
  o[0] = make_uint4(u[0],u[1],u[2],u[3]);
  o[1] = make_uint4(u[4],u[5],u[6],u[7]);
}

// ---------------- species tables: ZWs0 fp32, Zf fp32 (51x16) ----------------
__global__ __launch_bounds__(128) void k_spec(const void* __restrict__ Z,
                                              const void* __restrict__ Ws0,
                                              const void* __restrict__ bs0,
                                              const int* __restrict__ modep,
                                              float* __restrict__ ZWs0,
                                              float* __restrict__ Zf){
  int s = blockIdx.x, d = threadIdx.x;
  int md = *modep;
  float zk[16];
  #pragma unroll
  for(int k=0;k<16;k++) zk[k] = ldf(Z, s*16+k, md);
  float a = ldf(bs0, d, md);
  #pragma unroll
  for(int k=0;k<16;k++) a = fmaf(zk[k], ldf(Ws0, k*128+d, md), a);
  ZWs0[s*128+d] = a;
  if(d < 16) Zf[s*16+d] = zk[d];
}

// ---------------- pack W (Kx128 fp32) into MFMA B-fragment layout, bf16 ----------------
__global__ __launch_bounds__(256) void k_prepB(const float* __restrict__ W, int Ksteps,
                                               uint16_t* __restrict__ Bf){
  int idx = blockIdx.x*256 + threadIdx.x;
  int total = Ksteps*8*64;
  if(idx >= total) return;
  int l = idx & 63, nt = (idx>>6)&7, kk = idx>>9;
  int kbase = kk*32 + (l>>4)*8;
  int dim = nt*16 + (l&15);
  uint32_t u[4];
  #pragma unroll
  for(int t=0;t<4;t++){
    float f0 = W[(size_t)(kbase+2*t)*128 + dim];
    float f1 = W[(size_t)(kbase+2*t+1)*128 + dim];
    u[t] = packbf(f0,f1);
  }
  ((uint4*)Bf)[idx] = make_uint4(u[0],u[1],u[2],u[3]);
}

// pack all 12 onsite 128x128 weights into frags
__global__ __launch_bounds__(256) void k_prepW(const float* __restrict__ conv,
                                               uint16_t* __restrict__ Wf){
  int idx = blockIdx.x*256 + threadIdx.x;
  if(idx >= 12*2048) return;
  int wi = idx>>11, r = idx&2047;
  int l = r & 63, nt = (r>>6)&7, kk = r>>9;
  const float* W = conv + ((wi<6) ? (OFF_WA + wi*16384) : (OFF_WB + (wi-6)*16384));
  int kbase = kk*32 + (l>>4)*8;
  int dim = nt*16 + (l&15);
  uint32_t u[4];
  #pragma unroll
  for(int t=0;t<4;t++){
    float f0 = W[(size_t)(kbase+2*t)*128 + dim];
    float f1 = W[(size_t)(kbase+2*t+1)*128 + dim];
    u[t] = packbf(f0,f1);
  }
  ((uint4*)Wf)[idx] = make_uint4(u[0],u[1],u[2],u[3]);
}

// ---------------- layer-0 fused: scatter into LDS A-frags + MFMA GEMM ----------------
// block = 4 waves = one mtile (16 nodes). LDS tile: 8 ksteps x 64 slots x 8 bf16, XOR-swizzled.
__global__ __launch_bounds__(256) void k_msg0f(const int* __restrict__ offs,
                                               const int* __restrict__ sps,
                                               const uint16_t* __restrict__ gs,
                                               const float* __restrict__ Zf,
                                               const uint16_t* __restrict__ Bf,
                                               const int* __restrict__ species,
                                               const float* __restrict__ ZWs0,
                                               float* __restrict__ zi){
  __shared__ uint16_t ldsA[8*64*8];   // 8 KB
  int w = threadIdx.x>>6, l = threadIdx.x&63;
  int n0 = blockIdx.x*16;
  int u = l&31, dup = l>>5;
  int b = u>>1, zk0 = (u&1)*8;
  // phase A: 4 nodes per wave (fp32 Zf reads, no unpack)
  for(int i=0;i<4;i++){
    int m = w*4 + i;
    int n = n0 + m;
    float acc[8];
    #pragma unroll
    for(int j=0;j<8;j++) acc[j]=0.f;
    int beg = offs[n], end = offs[n+1];
    for(int ei=beg+dup; ei<end; ei+=2){
      int sp = sps[ei];
      float g = bf2f(gs[(size_t)ei*16 + b]);
      float4 za = *(const float4*)(Zf + sp*16 + zk0);
      float4 zb = *(const float4*)(Zf + sp*16 + zk0 + 4);
      acc[0]=fmaf(g,za.x,acc[0]); acc[1]=fmaf(g,za.y,acc[1]);
      acc[2]=fmaf(g,za.z,acc[2]); acc[3]=fmaf(g,za.w,acc[3]);
      acc[4]=fmaf(g,zb.x,acc[4]); acc[5]=fmaf(g,zb.y,acc[5]);
      acc[6]=fmaf(g,zb.z,acc[6]); acc[7]=fmaf(g,zb.w,acc[7]);
    }
    #pragma unroll
    for(int j=0;j<8;j++) acc[j] += __shfl(acc[j], l^32);
    if(dup==0){
      uint32_t p0 = packbf(acc[0],acc[1]), p1 = packbf(acc[2],acc[3]);
      uint32_t p2 = packbf(acc[4],acc[5]), p3 = packbf(acc[6],acc[7]);
      int kk = u>>2, q = u&3;
      int p = q*16 + m;
      int slot = kk*64 + (p ^ kk);
      *(uint4*)(&ldsA[slot*8]) = make_uint4(p0,p1,p2,p3);
    }
  }
  __syncthreads();
  // phase B: wave w -> ntiles w and w+4
  floatx4 acc1 = (floatx4){0.f,0.f,0.f,0.f};
  floatx4 acc2 = (floatx4){0.f,0.f,0.f,0.f};
  const short8* Bp = (const short8*)Bf;
  int nt1 = w, nt2 = w+4;
  #pragma unroll
  for(int kk=0;kk<8;kk++){
    short8 a = *(const short8*)(&ldsA[(kk*64 + (l^kk))*8]);
    short8 b1 = Bp[(size_t)(kk*8+nt1)*64 + l];
    short8 b2 = Bp[(size_t)(kk*8+nt2)*64 + l];
    acc1 = __builtin_amdgcn_mfma_f32_16x16x32_bf16(a, b1, acc1, 0,0,0);
    acc2 = __builtin_amdgcn_mfma_f32_16x16x32_bf16(a, b2, acc2, 0,0,0);
  }
  int col = l&15, quad = l>>4;
  #pragma unroll
  for(int reg=0;reg<4;reg++){
    int node = n0 + quad*4 + reg;
    int sp = species[node];
    if((unsigned)sp >= 51) sp = 0;
    int d1 = nt1*16 + col, d2 = nt2*16 + col;
    zi[(size_t)node*128 + d1] = siluf(acc1[reg] + ZWs0[sp*128 + d1]);
    zi[(size_t)node*128 + d2] = siluf(acc2[reg] + ZWs0[sp*128 + d2]);
  }
}

// ---------------- layer-1 fused: 512 threads (8 waves), fp32 gathers, out->zacc ----------------
__global__ __launch_bounds__(512) void k_msg1f(const int* __restrict__ offs,
                                               const int* __restrict__ dsts,
                                               const uint16_t* __restrict__ gs,
                                               const float* __restrict__ zi,     // fp32 gather source
                                               const uint16_t* __restrict__ zib, // bf16, ksteps 64..67
                                               const uint16_t* __restrict__ Bf,
                                               const float* __restrict__ bias,
                                               float* __restrict__ zacc){
  __shared__ uint16_t ldsA[64*64*8];   // 64 KB
  int w = threadIdx.x>>6, l = threadIdx.x&63;
  int n0 = blockIdx.x*16;
  int b = l&15, ks = l>>4;
  int kk_mine = b*4 + ks;
  // phase A: 2 nodes per wave, fp32 z reads
  for(int i=0;i<2;i++){
    int m = w*2 + i;
    int n = n0 + m;
    float acc[32];
    #pragma unroll
    for(int j=0;j<32;j++) acc[j]=0.f;
    int beg = offs[n], end = offs[n+1];
    int ei = beg;
    for(; ei+2<=end; ei+=2){
      int dn0 = dsts[ei], dn1 = dsts[ei+1];
      float g0 = bf2f(gs[(size_t)ei*16 + b]);
      float g1 = bf2f(gs[(size_t)(ei+1)*16 + b]);
      const float4* z0p = (const float4*)(zi + (size_t)dn0*128 + ks*32);
      const float4* z1p = (const float4*)(zi + (size_t)dn1*128 + ks*32);
      #pragma unroll
      for(int q=0;q<4;q++){
        float4 x0 = z0p[q*2], x1 = z0p[q*2+1];
        acc[q*8+0]=fmaf(g0,x0.x,acc[q*8+0]); acc[q*8+1]=fmaf(g0,x0.y,acc[q*8+1]);
        acc[q*8+2]=fmaf(g0,x0.z,acc[q*8+2]); acc[q*8+3]=fmaf(g0,x0.w,acc[q*8+3]);
        acc[q*8+4]=fmaf(g0,x1.x,acc[q*8+4]); acc[q*8+5]=fmaf(g0,x1.y,acc[q*8+5]);
        acc[q*8+6]=fmaf(g0,x1.z,acc[q*8+6]); acc[q*8+7]=fmaf(g0,x1.w,acc[q*8+7]);
        float4 y0 = z1p[q*2], y1 = z1p[q*2+1];
        acc[q*8+0]=fmaf(g1,y0.x,acc[q*8+0]); acc[q*8+1]=fmaf(g1,y0.y,acc[q*8+1]);
        acc[q*8+2]=fmaf(g1,y0.z,acc[q*8+2]); acc[q*8+3]=fmaf(g1,y0.w,acc[q*8+3]);
        acc[q*8+4]=fmaf(g1,y1.x,acc[q*8+4]); acc[q*8+5]=fmaf(g1,y1.y,acc[q*8+5]);
        acc[q*8+6]=fmaf(g1,y1.z,acc[q*8+6]); acc[q*8+7]=fmaf(g1,y1.w,acc[q*8+7]);
      }
    }
    if(ei < end){
      int dn0 = dsts[ei];
      float g0 = bf2f(gs[(size_t)ei*16 + b]);
      const float4* z0p = (const float4*)(zi + (size_t)dn0*128 + ks*32);
      #pragma unroll
      for(int q=0;q<4;q++){
        float4 x0 = z0p[q*2], x1 = z0p[q*2+1];
        acc[q*8+0]=fmaf(g0,x0.x,acc[q*8+0]); acc[q*8+1]=fmaf(g0,x0.y,acc[q*8+1]);
        acc[q*8+2]=fmaf(g0,x0.z,acc[q*8+2]); acc[q*8+3]=fmaf(g0,x0.w,acc[q*8+3]);
        acc[q*8+4]=fmaf(g0,x1.x,acc[q*8+4]); acc[q*8+5]=fmaf(g0,x1.y,acc[q*8+5]);
        acc[q*8+6]=fmaf(g0,x1.z,acc[q*8+6]); acc[q*8+7]=fmaf(g0,x1.w,acc[q*8+7]);
      }
    }
    #pragma unroll
    for(int g4=0; g4<4; g4++){
      uint32_t p0 = packbf(acc[g4*8+0],acc[g4*8+1]);
      uint32_t p1 = packbf(acc[g4*8+2],acc[g4*8+3]);
      uint32_t p2 = packbf(acc[g4*8+4],acc[g4*8+5]);
      uint32_t p3 = packbf(acc[g4*8+6],acc[g4*8+7]);
      int p = g4*16 + m;
      int slot = kk_mine*64 + (p ^ kk_mine);
      *(uint4*)(&ldsA[slot*8]) = make_uint4(p0,p1,p2,p3);
    }
  }
  __syncthreads();
  // phase B: wave w -> ntile w; ksteps 0..63 from LDS, 64..67 from zib
  floatx4 acc1 = (floatx4){0.f,0.f,0.f,0.f};
  const short8* Bp = (const short8*)Bf;
  int col = l&15, quad = l>>4;
  for(int kk=0;kk<64;kk++){
    short8 a = *(const short8*)(&ldsA[(kk*64 + (l^kk))*8]);
    short8 b1 = Bp[(size_t)(kk*8+w)*64 + l];
    acc1 = __builtin_amdgcn_mfma_f32_16x16x32_bf16(a, b1, acc1, 0,0,0);
  }
  #pragma unroll
  for(int kk=64;kk<KS1;kk++){
    uint4 za = *(const uint4*)(zib + (size_t)(n0+col)*128 + (kk-64)*32 + quad*8);
    union { short8 s; uint4 u; } A; A.u = za;
    short8 b1 = Bp[(size_t)(kk*8+w)*64 + l];
    acc1 = __builtin_amdgcn_mfma_f32_16x16x32_bf16(A.s, b1, acc1, 0,0,0);
  }
  #pragma unroll
  for(int reg=0;reg<4;reg++){
    int node = n0 + quad*4 + reg;
    int d1 = w*16 + col;
    zacc[(size_t)node*128 + d1] = siluf(acc1[reg] + bias[d1]);
  }
}

// ---------------- onsite via MFMA: 3 x (h=silu(z@Wa+ba); z+=h@Wb+bb) ----------------
__global__ __launch_bounds__(128) void k_onsite(float* __restrict__ zi,
                                                const uint16_t* __restrict__ Waf,
                                                const float* __restrict__ ba,
                                                const uint16_t* __restrict__ Wbf,
                                                const float* __restrict__ bb,
                                                void* __restrict__ outb,
                                                long off1, int st1,
                                                long off2, int st2,
                                                const int* __restrict__ modep,
                                                uint16_t* __restrict__ zib){
  __shared__ float zbuf[2][16*132];
  __shared__ float hbuf[2][16*132];
  int w = threadIdx.x>>6, l = threadIdx.x&63;
  int mtile = blockIdx.x*2 + w;
  int n0 = mtile*16;
  int md = *modep;
  float* zb = zbuf[w];
  float* hb = hbuf[w];
  #pragma unroll
  for(int i=0;i<8;i++){
    int flat = (i*64 + l)*4;
    int node = flat>>7, k = flat&127;
    *(float4*)(zb + node*132 + k) = *(const float4*)(zi + (size_t)(n0+node)*128 + k);
  }
  __syncthreads();
  int m = l&15, q = l>>4;
  for(int j=0;j<3;j++){
    const short8* Ba = (const short8*)Waf + (size_t)j*2048 + l;
    floatx4 acc[8];
    #pragma unroll
    for(int t=0;t<8;t++) acc[t] = (floatx4){0.f,0.f,0.f,0.f};
    #pragma unroll
    for(int kk=0;kk<4;kk++){
      const float* zp = zb + m*132 + kk*32 + q*8;
      float4 a0 = *(const float4*)zp, a1 = *(const float4*)(zp+4);
      union { short8 s; uint32_t u[4]; } A;
      A.u[0]=packbf(a0.x,a0.y); A.u[1]=packbf(a0.z,a0.w);
      A.u[2]=packbf(a1.x,a1.y); A.u[3]=packbf(a1.z,a1.w);
      #pragma unroll
      for(int nt=0;nt<8;nt++){
        short8 bfr = Ba[(size_t)(kk*8+nt)*64];
        acc[nt] = __builtin_amdgcn_mfma_f32_16x16x32_bf16(A.s, bfr, acc[nt], 0,0,0);
      }
    }
    #pragma unroll
    for(int nt=0;nt<8;nt++){
      int dim = nt*16 + m;
      float bv = ba[j*128+dim];
      #pragma unroll
      for(int reg=0;reg<4;reg++)
        hb[(q*4+reg)*132 + dim] = siluf(acc[nt][reg] + bv);
    }
    __syncthreads();
    const short8* Bb = (const short8*)Wbf + (size_t)j*2048 + l;
    floatx4 acc2[8];
    #pragma unroll
    for(int t=0;t<8;t++) acc2[t] = (floatx4){0.f,0.f,0.f,0.f};
    #pragma unroll
    for(int kk=0;kk<4;kk++){
      const float* hp = hb + m*132 + kk*32 + q*8;
      float4 a0 = *(const float4*)hp, a1 = *(const float4*)(hp+4);
      union { short8 s; uint32_t u[4]; } A;
      A.u[0]=packbf(a0.x,a0.y); A.u[1]=packbf(a0.z,a0.w);
      A.u[2]=packbf(a1.x,a1.y); A.u[3]=packbf(a1.z,a1.w);
      #pragma unroll
      for(int nt=0;nt<8;nt++){
        short8 bfr = Bb[(size_t)(kk*8+nt)*64];
        acc2[nt] = __builtin_amdgcn_mfma_f32_16x16x32_bf16(A.s, bfr, acc2[nt], 0,0,0);
      }
    }
    __syncthreads();
    #pragma unroll
    for(int nt=0;nt<8;nt++){
      int dim = nt*16 + m;
      float bv = bb[j*128+dim];
      #pragma unroll
      for(int reg=0;reg<4;reg++){
        int idx = (q*4+reg)*132 + dim;
        zb[idx] = zb[idx] + acc2[nt][reg] + bv;
      }
    }
    __syncthreads();
  }
  #pragma unroll
  for(int i=0;i<8;i++){
    int flat = (i*64 + l)*4;
    int node = flat>>7, k = flat&127;
    float4 v = *(float4*)(zb + node*132 + k);
    int n = n0 + node;
    *(float4*)(zi + (size_t)n*128 + k) = v;
    uint2 pv = make_uint2(packbf(v.x,v.y), packbf(v.z,v.w));
    if(zib) *(uint2*)(zib + (size_t)n*128 + k) = pv;
    if(md==1){
      uint16_t* ob = (uint16_t*)outb;
      *(uint2*)(ob + off1 + (long)n*st1 + k) = pv;
      if(off2 >= 0) *(uint2*)(ob + off2 + (long)n*st2 + k) = pv;
    } else {
      float* ob = (float*)outb;
      *(float4*)(ob + off1 + (long)n*st1 + k) = v;
      if(off2 >= 0) *(float4*)(ob + off2 + (long)n*st2 + k) = v;
    }
  }
}

extern "C" void kernel_launch(void* const* d_in, const int* in_sizes, int n_in,
                              void* d_out, int out_size, void* d_ws, size_t ws_size,
                              hipStream_t stream){
  const int* species = (const int*)d_in[0];
  const int* esrc    = (const int*)d_in[1];
  const int* edst    = (const int*)d_in[2];
  const void* dist   = d_in[3];
  const void* swit   = d_in[4];
  const void* Z      = d_in[5];
  const void* Ws0    = d_in[6];
  const void* bs0    = d_in[7];
  const void* V0     = d_in[8];
  const void* Ws1    = d_in[9];
  const void* bs1    = d_in[10];
  const void* V1     = d_in[11];
  const void* Wa     = d_in[12];
  const void* ba     = d_in[13];
  const void* Wb     = d_in[14];
  const void* bb     = d_in[15];

  char* ws = (char*)d_ws;
  size_t off = 0;
  auto alloc = [&](size_t bytes)->void*{ void* p = ws + off; off = (off + bytes + 255) & ~(size_t)255; return p; };
  int*      offs = (int*)     alloc((size_t)(NNODES+1)*4);
  int*      cur  = (int*)     alloc((size_t)NNODES*4);
  int*      pos  = (int*)     alloc((size_t)NEDGES*4);
  int*      dsts = (int*)     alloc((size_t)NEDGES*4);
  int*      sps  = (int*)     alloc((size_t)NEDGES*4);
  uint16_t* gs   = (uint16_t*)alloc((size_t)NEDGES*16*2);      // 12.8 MB
  float*    zi   = (float*)   alloc((size_t)NNODES*128*4);     // 10.24 MB
  float*    zacc = (float*)   alloc((size_t)NNODES*128*4);     // 10.24 MB
  uint16_t* zib  = (uint16_t*)alloc((size_t)NNODES*128*2);     // 5.12 MB
  float*    ZWs0 = (float*)   alloc((size_t)51*128*4);
  float*    Zf   = (float*)   alloc((size_t)51*16*4);
  float*    conv = (float*)   alloc((size_t)N_CONV*4);         // 2.04 MB
  uint16_t* Bf0  = (uint16_t*)alloc((size_t)8*8*64*8*2);       // 64 KB
  uint16_t* Bf1  = (uint16_t*)alloc((size_t)KS1*8*64*8*2);     // 557 KB
  uint16_t* Wfr  = (uint16_t*)alloc((size_t)12*16384*2);       // 384 KB
  int*      mode = (int*)     alloc(256);

  const int EB = (NEDGES+255)/256;
  hipMemsetAsync(cur, 0, NNODES*4, stream);
  k_probe<<<1,64,0,stream>>>(dist, mode);
  k_conv <<<(N_CONV+255)/256,256,0,stream>>>(V0, Ws1, bs1, V1, Wa, ba, Wb, bb, mode, conv);
  k_hist <<<EB,256,0,stream>>>(esrc, cur);
  k_scan <<<1,64,0,stream>>>(cur, offs);
  k_fill <<<EB,256,0,stream>>>(esrc, edst, species, cur, dsts, sps, pos);
  k_G    <<<EB,256,0,stream>>>(dist, swit, mode, pos, gs);
  k_spec <<<51,128,0,stream>>>(Z, Ws0, bs0, mode, ZWs0, Zf);
  k_prepB<<<(8*8*64+255)/256,256,0,stream>>>(conv+OFF_V0, 8,  Bf0);
  k_prepB<<<(64*8*64+255)/256,256,0,stream>>>(conv+OFF_V1, 64, Bf1);
  k_prepB<<<(4*8*64+255)/256,256,0,stream>>>(conv+OFF_WS1, 4, Bf1 + (size_t)64*8*64*8);
  k_prepW<<<(12*2048+255)/256,256,0,stream>>>(conv, Wfr);

  const long ZIS = (long)NNODES*128;
  uint16_t* WaF0 = Wfr;
  uint16_t* WaF1 = Wfr + (size_t)3*16384;
  uint16_t* WbF0 = Wfr + (size_t)6*16384;
  uint16_t* WbF1 = Wfr + (size_t)9*16384;

  // layer 0 (fused scatter+GEMM)
  k_msg0f<<<MTILES,256,0,stream>>>(offs, sps, gs, Zf, Bf0, species, ZWs0, zi);
  k_onsite<<<MTILES/2,128,0,stream>>>(zi, WaF0, conv+OFF_BA, WbF0, conv+OFF_BB,
                                      d_out, ZIS, 256, (long)-1, 0, mode, zib);

  // layer 1 (fused; fp32 gathers from zi, output to zacc)
  k_msg1f<<<MTILES,512,0,stream>>>(offs, dsts, gs, zi, zib, Bf1, conv+OFF_BS1, zacc);
  k_onsite<<<MTILES/2,128,0,stream>>>(zacc, WaF1, conv+OFF_BA+384, WbF1, conv+OFF_BB+384,
                                      d_out, ZIS+128, 256, (long)0, 128, mode, (uint16_t*)nullptr);
}

// Round 8
// 470.906 us; speedup vs baseline: 1.2036x; 1.1979x over previous
//
#include <hip/hip_runtime.h>
#include <stdint.h>

#define NNODES 20000
#define NEDGES 400000
#define MTILES 1250   // 20000/16
#define KS1 68        // layer-1 msg GEMM ksteps: 64 (T@V1) + 4 (zi@Ws1)

typedef __attribute__((ext_vector_type(8))) short short8;
typedef __attribute__((ext_vector_type(4))) float floatx4;

__device__ __forceinline__ float bf2f(uint16_t u){ return __uint_as_float(((uint32_t)u)<<16); }
__device__ __forceinline__ uint16_t f2bf(float f){
  uint32_t x = __float_as_uint(f);
  x += 0x7FFFu + ((x>>16)&1u);
  return (uint16_t)(x>>16);
}
__device__ __forceinline__ uint32_t packbf(float a, float b){
  return (uint32_t)f2bf(a) | ((uint32_t)f2bf(b)<<16);
}
__device__ __forceinline__ float siluf(float x){ return x/(1.0f+__expf(-x)); }
__device__ __forceinline__ float ldf(const void* p, int i, int md){
  return (md==1) ? bf2f(((const uint16_t*)p)[i]) : ((const float*)p)[i];
}

// converted-weights layout (float elements within conv buffer)
#define OFF_V0   0
#define N_V0     32768
#define OFF_WS1  32768
#define N_WS1    16384
#define OFF_BS1  49152
#define N_BS1    128
#define OFF_V1   49280
#define N_V1     262144
#define OFF_WA   311424
#define N_WA     98304
#define OFF_BA   409728
#define N_BA     768
#define OFF_WB   410496
#define N_WB     98304
#define OFF_BB   508800
#define N_BB     768
#define N_CONV   509568

// ---------------- dtype probe ----------------
__global__ void k_probe(const void* dist, int* mode){
  if(threadIdx.x != 0 || blockIdx.x != 0) return;
  const float* f = (const float*)dist;
  const uint16_t* h = (const uint16_t*)dist;
  int okf = 1, okb = 1;
  for(int i=0;i<256;i++){
    float a = f[i];       okf &= (a >= 0.7f) & (a <= 5.1f);
    float b = bf2f(h[i]); okb &= (b >= 0.7f) & (b <= 5.1f);
  }
  *mode = okb ? 1 : (okf ? 0 : 1);
}

// ---------------- convert all weight tensors to fp32 ----------------
__global__ __launch_bounds__(256) void k_conv(const void* s0,const void* s1,const void* s2,const void* s3,
                                              const void* s4,const void* s5,const void* s6,const void* s7,
                                              const int* __restrict__ modep, float* __restrict__ dst){
  int md = *modep;
  int i = blockIdx.x*256 + threadIdx.x;
  if(i >= N_CONV) return;
  const void* src; int t = i;
  if(t < N_V0){src=s0;}
  else if((t-=N_V0) < N_WS1){src=s1;}
  else if((t-=N_WS1) < N_BS1){src=s2;}
  else if((t-=N_BS1) < N_V1){src=s3;}
  else if((t-=N_V1) < N_WA){src=s4;}
  else if((t-=N_WA) < N_BA){src=s5;}
  else if((t-=N_BA) < N_WB){src=s6;}
  else {t-=N_WB; src=s7;}
  dst[i] = ldf(src, t, md);
}

// ---------------- CSR build ----------------
__global__ __launch_bounds__(256) void k_hist(const int* __restrict__ src, int* __restrict__ cnt){
  int e = blockIdx.x*256 + threadIdx.x;
  if(e < NEDGES){
    int s = src[e];
    if((unsigned)s < NNODES) atomicAdd(&cnt[s], 1);
  }
}

__global__ __launch_bounds__(64) void k_scan(int* cnt_cur, int* offs){
  int t = threadIdx.x;
  const int chunk = (NNODES + 63)/64;   // 313
  int lo = t*chunk, hi = lo+chunk;
  if(lo > NNODES) lo = NNODES;
  if(hi > NNODES) hi = NNODES;
  int s = 0;
  for(int i=lo;i<hi;i++) s += cnt_cur[i];
  int v = s;
  #pragma unroll
  for(int d=1; d<64; d<<=1){
    int u = __shfl_up(v, d);
    if(t >= d) v += u;
  }
  int run = v - s;
  for(int i=lo;i<hi;i++){
    int c = cnt_cur[i];
    offs[i] = run;
    cnt_cur[i] = run;
    run += c;
  }
  if(t==63) offs[NNODES] = run;
}

__global__ __launch_bounds__(256) void k_fill(const int* __restrict__ src,
                                              const int* __restrict__ edst,
                                              const int* __restrict__ species,
                                              int* __restrict__ cur,
                                              int* __restrict__ dsts,
                                              int* __restrict__ sps,
                                              int* __restrict__ pos){
  int e = blockIdx.x*256 + threadIdx.x;
  if(e >= NEDGES) return;
  int s = src[e];
  if((unsigned)s >= NNODES) s = 0;
  int p = atomicAdd(&cur[s], 1);
  if((unsigned)p >= NEDGES) p = 0;
  pos[e] = p;
  int dn = edst[e];
  if((unsigned)dn >= NNODES) dn = 0;
  dsts[p] = dn;
  int sp = species[dn];
  if((unsigned)sp >= 51) sp = 0;
  sps[p] = sp;
}

// ---------------- radial basis -> sorted bf16 rows g_s[p][16] ----------------
__global__ __launch_bounds__(256) void k_G(const void* __restrict__ dist,
                                           const void* __restrict__ sw,
                                           const int* __restrict__ modep,
                                           const int* __restrict__ pos,
                                           uint16_t* __restrict__ gs){
  int e = blockIdx.x*256 + threadIdx.x;
  if(e >= NEDGES) return;
  int md = *modep;
  float r = ldf(dist, e, md);
  float w = ldf(sw, e, md);
  float rinv = 1.0f/r;
  const float sigma = 0.8f/15.0f;
  const float isig  = 15.0f/0.8f;
  uint32_t u[8];
  #pragma unroll
  for(int j=0;j<8;j++){
    float mu0 = 0.2f + sigma*(float)(2*j);
    float mu1 = 0.2f + sigma*(float)(2*j+1);
    float t0 = (rinv-mu0)*isig, t1 = (rinv-mu1)*isig;
    u[j] = packbf(w*__expf(-0.5f*t0*t0), w*__expf(-0.5f*t1*t1));
  }
  int p = pos[e];
  uint4* o = (uint4*)(gs + (size_t)p*16);
  o[0] = make_uint4(u[0],u[1],u[2],u[3]);
  o[1] = make_uint4(u[4],u[5],u[6],u[7]);
}

// ---------------- species tables: ZWs0 fp32, zfb bf16 (51x16) ----------------
__global__ __launch_bounds__(128) void k_spec(const void* __restrict__ Z,
                                              const void* __restrict__ Ws0,
                                              const void* __restrict__ bs0,
                                              const int* __restrict__ modep,
                                              float* __restrict__ ZWs0,
                                              uint16_t* __restrict__ zfb){
  int s = blockIdx.x, d = threadIdx.x;
  int md = *modep;
  float zk[16];
  #pragma unroll
  for(int k=0;k<16;k++) zk[k] = ldf(Z, s*16+k, md);
  float a = ldf(bs0, d, md);
  #pragma unroll
  for(int k=0;k<16;k++) a = fmaf(zk[k], ldf(Ws0, k*128+d, md), a);
  ZWs0[s*128+d] = a;
  if(d < 16) zfb[s*16+d] = f2bf(zk[d]);
}

// ---------------- pack W (Kx128 fp32) into MFMA B-fragment layout, bf16 ----------------
__global__ __launch_bounds__(256) void k_prepB(const float* __restrict__ W, int Ksteps,
                                               uint16_t* __restrict__ Bf){
  int idx = blockIdx.x*256 + threadIdx.x;
  int total = Ksteps*8*64;
  if(idx >= total) return;
  int l = idx & 63, nt = (idx>>6)&7, kk = idx>>9;
  int kbase = kk*32 + (l>>4)*8;
  int dim = nt*16 + (l&15);
  uint32_t u[4];
  #pragma unroll
  for(int t=0;t<4;t++){
    float f0 = W[(size_t)(kbase+2*t)*128 + dim];
    float f1 = W[(size_t)(kbase+2*t+1)*128 + dim];
    u[t] = packbf(f0,f1);
  }
  ((uint4*)Bf)[idx] = make_uint4(u[0],u[1],u[2],u[3]);
}

// pack all 12 onsite 128x128 weights into frags
__global__ __launch_bounds__(256) void k_prepW(const float* __restrict__ conv,
                                               uint16_t* __restrict__ Wf){
  int idx = blockIdx.x*256 + threadIdx.x;
  if(idx >= 12*2048) return;
  int wi = idx>>11, r = idx&2047;
  int l = r & 63, nt = (r>>6)&7, kk = r>>9;
  const float* W = conv + ((wi<6) ? (OFF_WA + wi*16384) : (OFF_WB + (wi-6)*16384));
  int kbase = kk*32 + (l>>4)*8;
  int dim = nt*16 + (l&15);
  uint32_t u[4];
  #pragma unroll
  for(int t=0;t<4;t++){
    float f0 = W[(size_t)(kbase+2*t)*128 + dim];
    float f1 = W[(size_t)(kbase+2*t+1)*128 + dim];
    u[t] = packbf(f0,f1);
  }
  ((uint4*)Wf)[idx] = make_uint4(u[0],u[1],u[2],u[3]);
}

// ---------------- layer-0 fused: MFMA phase A (T0^T = Zf^T @ G) + MFMA GEMM ----------------
// block = 4 waves = one mtile (16 nodes). LDS: 8 ksteps x 64 slots x 8 bf16.
__global__ __launch_bounds__(256) void k_msg0f(const int* __restrict__ offs,
                                               const int* __restrict__ sps,
                                               const uint16_t* __restrict__ gs,
                                               const uint16_t* __restrict__ zfb,
                                               const uint16_t* __restrict__ Bf,
                                               const int* __restrict__ species,
                                               const float* __restrict__ ZWs0,
                                               float* __restrict__ zi){
  __shared__ uint16_t ldsA[8*64*8];   // 8 KB
  int w = threadIdx.x>>6, l = threadIdx.x&63;
  int n0 = blockIdx.x*16;
  int col = l&15, quad = l>>4;
  // phase A: 4 nodes per wave; T0^T[zk][b] = sum_e zfb[sp_e][zk] * g[e][b]
  for(int i=0;i<4;i++){
    int m = w*4 + i;
    int n = n0 + m;
    int beg = offs[n], end = offs[n+1];
    floatx4 acc0 = (floatx4){0.f,0.f,0.f,0.f};
    for(int p0=beg; p0<end; p0+=32){
      int sp[8];
      union { short8 s; uint16_t u[8]; } Bg, Az;
      #pragma unroll
      for(int j=0;j<8;j++){
        int p = p0 + quad*8 + j;
        int pc = p < end ? p : beg;
        sp[j] = sps[pc];
        uint16_t g = gs[(size_t)pc*16 + col];
        Bg.u[j] = (p < end) ? g : (uint16_t)0;
      }
      #pragma unroll
      for(int j=0;j<8;j++)
        Az.u[j] = zfb[sp[j]*16 + col];
      acc0 = __builtin_amdgcn_mfma_f32_16x16x32_bf16(Az.s, Bg.s, acc0, 0,0,0);
    }
    // value (zk = quad*4+reg, b = col): K = b*16 + zk
    int K0 = col*16 + quad*4;
    int kk = K0>>5, qt = (K0>>3)&3, jt = K0&7;
    int slot = kk*64 + ((qt*16 + m) ^ (kk>>2));
    uint32_t lo = packbf(acc0[0], acc0[1]);
    uint32_t hi = packbf(acc0[2], acc0[3]);
    *(uint2*)(&ldsA[slot*8 + jt]) = make_uint2(lo, hi);
  }
  __syncthreads();
  // phase B: wave w -> ntiles w and w+4
  floatx4 acc1 = (floatx4){0.f,0.f,0.f,0.f};
  floatx4 acc2 = (floatx4){0.f,0.f,0.f,0.f};
  const short8* Bp = (const short8*)Bf;
  int nt1 = w, nt2 = w+4;
  #pragma unroll
  for(int kk=0;kk<8;kk++){
    short8 a = *(const short8*)(&ldsA[(kk*64 + (l^(kk>>2)))*8]);
    short8 b1 = Bp[(size_t)(kk*8+nt1)*64 + l];
    short8 b2 = Bp[(size_t)(kk*8+nt2)*64 + l];
    acc1 = __builtin_amdgcn_mfma_f32_16x16x32_bf16(a, b1, acc1, 0,0,0);
    acc2 = __builtin_amdgcn_mfma_f32_16x16x32_bf16(a, b2, acc2, 0,0,0);
  }
  #pragma unroll
  for(int reg=0;reg<4;reg++){
    int node = n0 + quad*4 + reg;
    int sp = species[node];
    if((unsigned)sp >= 51) sp = 0;
    int d1 = nt1*16 + col, d2 = nt2*16 + col;
    zi[(size_t)node*128 + d1] = siluf(acc1[reg] + ZWs0[sp*128 + d1]);
    zi[(size_t)node*128 + d2] = siluf(acc2[reg] + ZWs0[sp*128 + d2]);
  }
}

// ---------------- layer-1 fused: MFMA phase A (T^T = Z^T @ G) + MFMA GEMM (KS1=68) ----------------
// block = 8 waves (512 thr) = one mtile. LDS: 64 ksteps x 64 slots x 8 bf16 = 64 KB.
__global__ __launch_bounds__(512) void k_msg1f(const int* __restrict__ offs,
                                               const int* __restrict__ dsts,
                                               const uint16_t* __restrict__ gs,
                                               const uint16_t* __restrict__ zib,
                                               const uint16_t* __restrict__ Bf,
                                               const float* __restrict__ bias,
                                               float* __restrict__ zacc){
  __shared__ uint16_t ldsA[64*64*8];   // 64 KB
  int w = threadIdx.x>>6, l = threadIdx.x&63;
  int n0 = blockIdx.x*16;
  int col = l&15, quad = l>>4;
  // phase A: 2 nodes per wave
  for(int i=0;i<2;i++){
    int m = w*2 + i;
    int n = n0 + m;
    int beg = offs[n], end = offs[n+1];
    floatx4 acc[8];
    #pragma unroll
    for(int t=0;t<8;t++) acc[t] = (floatx4){0.f,0.f,0.f,0.f};
    for(int p0=beg; p0<end; p0+=32){
      int dn[8];
      union { short8 s; uint16_t u[8]; } Bg;
      #pragma unroll
      for(int j=0;j<8;j++){
        int p = p0 + quad*8 + j;
        int pc = p < end ? p : beg;
        dn[j] = dsts[pc];
        uint16_t g = gs[(size_t)pc*16 + col];
        Bg.u[j] = (p < end) ? g : (uint16_t)0;
      }
      #pragma unroll
      for(int mt=0;mt<8;mt++){
        union { short8 s; uint16_t u[8]; } Az;
        #pragma unroll
        for(int j=0;j<8;j++)
          Az.u[j] = zib[(size_t)dn[j]*128 + mt*16 + col];
        acc[mt] = __builtin_amdgcn_mfma_f32_16x16x32_bf16(Az.s, Bg.s, acc[mt], 0,0,0);
      }
    }
    // value (kz = mt*16 + quad*4+reg, b = col): K = b*128 + kz; reg -> 4 consecutive K
    #pragma unroll
    for(int mt=0;mt<8;mt++){
      int K0 = col*128 + mt*16 + quad*4;
      int kk = K0>>5, qt = (K0>>3)&3, jt = K0&7;
      int slot = kk*64 + ((qt*16 + m) ^ (kk>>2));
      uint32_t lo = packbf(acc[mt][0], acc[mt][1]);
      uint32_t hi = packbf(acc[mt][2], acc[mt][3]);
      *(uint2*)(&ldsA[slot*8 + jt]) = make_uint2(lo, hi);
    }
  }
  __syncthreads();
  // phase B: wave w -> ntile w; ksteps 0..63 from LDS, 64..67 from zib (zself via Ws1 frags)
  floatx4 acc1 = (floatx4){0.f,0.f,0.f,0.f};
  const short8* Bp = (const short8*)Bf;
  for(int kk=0;kk<64;kk++){
    short8 a = *(const short8*)(&ldsA[(kk*64 + (l^(kk>>2)))*8]);
    short8 b1 = Bp[(size_t)(kk*8+w)*64 + l];
    acc1 = __builtin_amdgcn_mfma_f32_16x16x32_bf16(a, b1, acc1, 0,0,0);
  }
  #pragma unroll
  for(int kk=64;kk<KS1;kk++){
    uint4 za = *(const uint4*)(zib + (size_t)(n0+col)*128 + (kk-64)*32 + quad*8);
    union { short8 s; uint4 u; } A; A.u = za;
    short8 b1 = Bp[(size_t)(kk*8+w)*64 + l];
    acc1 = __builtin_amdgcn_mfma_f32_16x16x32_bf16(A.s, b1, acc1, 0,0,0);
  }
  #pragma unroll
  for(int reg=0;reg<4;reg++){
    int node = n0 + quad*4 + reg;
    int d1 = w*16 + col;
    zacc[(size_t)node*128 + d1] = siluf(acc1[reg] + bias[d1]);
  }
}

// ---------------- onsite via MFMA: 3 x (h=silu(z@Wa+ba); z+=h@Wb+bb) ----------------
__global__ __launch_bounds__(128) void k_onsite(float* __restrict__ zi,
                                                const uint16_t* __restrict__ Waf,
                                                const float* __restrict__ ba,
                                                const uint16_t* __restrict__ Wbf,
                                                const float* __restrict__ bb,
                                                void* __restrict__ outb,
                                                long off1, int st1,
                                                long off2, int st2,
                                                const int* __restrict__ modep,
                                                uint16_t* __restrict__ zib){
  __shared__ float zbuf[2][16*132];
  __shared__ float hbuf[2][16*132];
  int w = threadIdx.x>>6, l = threadIdx.x&63;
  int mtile = blockIdx.x*2 + w;
  int n0 = mtile*16;
  int md = *modep;
  float* zb = zbuf[w];
  float* hb = hbuf[w];
  #pragma unroll
  for(int i=0;i<8;i++){
    int flat = (i*64 + l)*4;
    int node = flat>>7, k = flat&127;
    *(float4*)(zb + node*132 + k) = *(const float4*)(zi + (size_t)(n0+node)*128 + k);
  }
  __syncthreads();
  int m = l&15, q = l>>4;
  for(int j=0;j<3;j++){
    const short8* Ba = (const short8*)Waf + (size_t)j*2048 + l;
    floatx4 acc[8];
    #pragma unroll
    for(int t=0;t<8;t++) acc[t] = (floatx4){0.f,0.f,0.f,0.f};
    #pragma unroll
    for(int kk=0;kk<4;kk++){
      const float* zp = zb + m*132 + kk*32 + q*8;
      float4 a0 = *(const float4*)zp, a1 = *(const float4*)(zp+4);
      union { short8 s; uint32_t u[4]; } A;
      A.u[0]=packbf(a0.x,a0.y); A.u[1]=packbf(a0.z,a0.w);
      A.u[2]=packbf(a1.x,a1.y); A.u[3]=packbf(a1.z,a1.w);
      #pragma unroll
      for(int nt=0;nt<8;nt++){
        short8 bfr = Ba[(size_t)(kk*8+nt)*64];
        acc[nt] = __builtin_amdgcn_mfma_f32_16x16x32_bf16(A.s, bfr, acc[nt], 0,0,0);
      }
    }
    #pragma unroll
    for(int nt=0;nt<8;nt++){
      int dim = nt*16 + m;
      float bv = ba[j*128+dim];
      #pragma unroll
      for(int reg=0;reg<4;reg++)
        hb[(q*4+reg)*132 + dim] = siluf(acc[nt][reg] + bv);
    }
    __syncthreads();
    const short8* Bb = (const short8*)Wbf + (size_t)j*2048 + l;
    floatx4 acc2[8];
    #pragma unroll
    for(int t=0;t<8;t++) acc2[t] = (floatx4){0.f,0.f,0.f,0.f};
    #pragma unroll
    for(int kk=0;kk<4;kk++){
      const float* hp = hb + m*132 + kk*32 + q*8;
      float4 a0 = *(const float4*)hp, a1 = *(const float4*)(hp+4);
      union { short8 s; uint32_t u[4]; } A;
      A.u[0]=packbf(a0.x,a0.y); A.u[1]=packbf(a0.z,a0.w);
      A.u[2]=packbf(a1.x,a1.y); A.u[3]=packbf(a1.z,a1.w);
      #pragma unroll
      for(int nt=0;nt<8;nt++){
        short8 bfr = Bb[(size_t)(kk*8+nt)*64];
        acc2[nt] = __builtin_amdgcn_mfma_f32_16x16x32_bf16(A.s, bfr, acc2[nt], 0,0,0);
      }
    }
    __syncthreads();
    #pragma unroll
    for(int nt=0;nt<8;nt++){
      int dim = nt*16 + m;
      float bv = bb[j*128+dim];
      #pragma unroll
      for(int reg=0;reg<4;reg++){
        int idx = (q*4+reg)*132 + dim;
        zb[idx] = zb[idx] + acc2[nt][reg] + bv;
      }
    }
    __syncthreads();
  }
  #pragma unroll
  for(int i=0;i<8;i++){
    int flat = (i*64 + l)*4;
    int node = flat>>7, k = flat&127;
    float4 v = *(float4*)(zb + node*132 + k);
    int n = n0 + node;
    *(float4*)(zi + (size_t)n*128 + k) = v;
    uint2 pv = make_uint2(packbf(v.x,v.y), packbf(v.z,v.w));
    if(zib) *(uint2*)(zib + (size_t)n*128 + k) = pv;
    if(md==1){
      uint16_t* ob = (uint16_t*)outb;
      *(uint2*)(ob + off1 + (long)n*st1 + k) = pv;
      if(off2 >= 0) *(uint2*)(ob + off2 + (long)n*st2 + k) = pv;
    } else {
      float* ob = (float*)outb;
      *(float4*)(ob + off1 + (long)n*st1 + k) = v;
      if(off2 >= 0) *(float4*)(ob + off2 + (long)n*st2 + k) = v;
    }
  }
}

extern "C" void kernel_launch(void* const* d_in, const int* in_sizes, int n_in,
                              void* d_out, int out_size, void* d_ws, size_t ws_size,
                              hipStream_t stream){
  const int* species = (const int*)d_in[0];
  const int* esrc    = (const int*)d_in[1];
  const int* edst    = (const int*)d_in[2];
  const void* dist   = d_in[3];
  const void* swit   = d_in[4];
  const void* Z      = d_in[5];
  const void* Ws0    = d_in[6];
  const void* bs0    = d_in[7];
  const void* V0     = d_in[8];
  const void* Ws1    = d_in[9];
  const void* bs1    = d_in[10];
  const void* V1     = d_in[11];
  const void* Wa     = d_in[12];
  const void* ba     = d_in[13];
  const void* Wb     = d_in[14];
  const void* bb     = d_in[15];

  char* ws = (char*)d_ws;
  size_t off = 0;
  auto alloc = [&](size_t bytes)->void*{ void* p = ws + off; off = (off + bytes + 255) & ~(size_t)255; return p; };
  int*      offs = (int*)     alloc((size_t)(NNODES+1)*4);
  int*      cur  = (int*)     alloc((size_t)NNODES*4);
  int*      pos  = (int*)     alloc((size_t)NEDGES*4);
  int*      dsts = (int*)     alloc((size_t)NEDGES*4);
  int*      sps  = (int*)     alloc((size_t)NEDGES*4);
  uint16_t* gs   = (uint16_t*)alloc((size_t)NEDGES*16*2);      // 12.8 MB
  float*    zi   = (float*)   alloc((size_t)NNODES*128*4);     // 10.24 MB
  float*    zacc = (float*)   alloc((size_t)NNODES*128*4);     // 10.24 MB
  uint16_t* zib  = (uint16_t*)alloc((size_t)NNODES*128*2);     // 5.12 MB
  float*    ZWs0 = (float*)   alloc((size_t)51*128*4);
  uint16_t* zfb  = (uint16_t*)alloc((size_t)51*16*2);
  float*    conv = (float*)   alloc((size_t)N_CONV*4);         // 2.04 MB
  uint16_t* Bf0  = (uint16_t*)alloc((size_t)8*8*64*8*2);       // 64 KB
  uint16_t* Bf1  = (uint16_t*)alloc((size_t)KS1*8*64*8*2);     // 557 KB
  uint16_t* Wfr  = (uint16_t*)alloc((size_t)12*16384*2);       // 384 KB
  int*      mode = (int*)     alloc(256);

  const int EB = (NEDGES+255)/256;
  hipMemsetAsync(cur, 0, NNODES*4, stream);
  k_probe<<<1,64,0,stream>>>(dist, mode);
  k_conv <<<(N_CONV+255)/256,256,0,stream>>>(V0, Ws1, bs1, V1, Wa, ba, Wb, bb, mode, conv);
  k_hist <<<EB,256,0,stream>>>(esrc, cur);
  k_scan <<<1,64,0,stream>>>(cur, offs);
  k_fill <<<EB,256,0,stream>>>(esrc, edst, species, cur, dsts, sps, pos);
  k_G    <<<EB,256,0,stream>>>(dist, swit, mode, pos, gs);
  k_spec <<<51,128,0,stream>>>(Z, Ws0, bs0, mode, ZWs0, zfb);
  k_prepB<<<(8*8*64+255)/256,256,0,stream>>>(conv+OFF_V0, 8,  Bf0);
  k_prepB<<<(64*8*64+255)/256,256,0,stream>>>(conv+OFF_V1, 64, Bf1);
  k_prepB<<<(4*8*64+255)/256,256,0,stream>>>(conv+OFF_WS1, 4, Bf1 + (size_t)64*8*64*8);
  k_prepW<<<(12*2048+255)/256,256,0,stream>>>(conv, Wfr);

  const long ZIS = (long)NNODES*128;
  uint16_t* WaF0 = Wfr;
  uint16_t* WaF1 = Wfr + (size_t)3*16384;
  uint16_t* WbF0 = Wfr + (size_t)6*16384;
  uint16_t* WbF1 = Wfr + (size_t)9*16384;

  // layer 0 (fused MFMA scatter+GEMM)
  k_msg0f<<<MTILES,256,0,stream>>>(offs, sps, gs, zfb, Bf0, species, ZWs0, zi);
  k_onsite<<<MTILES/2,128,0,stream>>>(zi, WaF0, conv+OFF_BA, WbF0, conv+OFF_BB,
                                      d_out, ZIS, 256, (long)-1, 0, mode, zib);

  // layer 1 (fused MFMA scatter+GEMM incl. zself ksteps)
  k_msg1f<<<MTILES,512,0,stream>>>(offs, dsts, gs, zib, Bf1, conv+OFF_BS1, zacc);
  k_onsite<<<MTILES/2,128,0,stream>>>(zacc, WaF1, conv+OFF_BA+384, WbF1, conv+OFF_BB+384,
                                      d_out, ZIS+128, 256, (long)0, 128, mode, (uint16_t*)nullptr);
}

// Round 9
// 411.309 us; speedup vs baseline: 1.3780x; 1.1449x over previous
//
#include <hip/hip_runtime.h>
#include <stdint.h>

#define NNODES 20000
#define NEDGES 400000
#define MTILES 1250   // 20000/16
#define KS1 68        // layer-1 msg GEMM ksteps: 64 (T@V1) + 4 (zi@Ws1)

typedef __attribute__((ext_vector_type(8))) short short8;
typedef __attribute__((ext_vector_type(4))) float floatx4;

__device__ __forceinline__ float bf2f(uint16_t u){ return __uint_as_float(((uint32_t)u)<<16); }
__device__ __forceinline__ uint16_t f2bf(float f){
  uint32_t x = __float_as_uint(f);
  x += 0x7FFFu + ((x>>16)&1u);
  return (uint16_t)(x>>16);
}
__device__ __forceinline__ uint32_t packbf(float a, float b){
  return (uint32_t)f2bf(a) | ((uint32_t)f2bf(b)<<16);
}
__device__ __forceinline__ float siluf(float x){ return x/(1.0f+__expf(-x)); }
__device__ __forceinline__ float ldf(const void* p, int i, int md){
  return (md==1) ? bf2f(((const uint16_t*)p)[i]) : ((const float*)p)[i];
}

// converted-weights layout (float elements within conv buffer)
#define OFF_V0   0
#define N_V0     32768
#define OFF_WS1  32768
#define N_WS1    16384
#define OFF_BS1  49152
#define N_BS1    128
#define OFF_V1   49280
#define N_V1     262144
#define OFF_WA   311424
#define N_WA     98304
#define OFF_BA   409728
#define N_BA     768
#define OFF_WB   410496
#define N_WB     98304
#define OFF_BB   508800
#define N_BB     768
#define N_CONV   509568

// ---------------- dtype probe ----------------
__global__ void k_probe(const void* dist, int* mode){
  if(threadIdx.x != 0 || blockIdx.x != 0) return;
  const float* f = (const float*)dist;
  const uint16_t* h = (const uint16_t*)dist;
  int okf = 1, okb = 1;
  for(int i=0;i<256;i++){
    float a = f[i];       okf &= (a >= 0.7f) & (a <= 5.1f);
    float b = bf2f(h[i]); okb &= (b >= 0.7f) & (b <= 5.1f);
  }
  *mode = okb ? 1 : (okf ? 0 : 1);
}

// ---------------- convert all weight tensors to fp32 ----------------
__global__ __launch_bounds__(256) void k_conv(const void* s0,const void* s1,const void* s2,const void* s3,
                                              const void* s4,const void* s5,const void* s6,const void* s7,
                                              const int* __restrict__ modep, float* __restrict__ dst){
  int md = *modep;
  int i = blockIdx.x*256 + threadIdx.x;
  if(i >= N_CONV) return;
  const void* src; int t = i;
  if(t < N_V0){src=s0;}
  else if((t-=N_V0) < N_WS1){src=s1;}
  else if((t-=N_WS1) < N_BS1){src=s2;}
  else if((t-=N_BS1) < N_V1){src=s3;}
  else if((t-=N_V1) < N_WA){src=s4;}
  else if((t-=N_WA) < N_BA){src=s5;}
  else if((t-=N_BA) < N_WB){src=s6;}
  else {t-=N_WB; src=s7;}
  dst[i] = ldf(src, t, md);
}

// ---------------- CSR build ----------------
__global__ __launch_bounds__(256) void k_hist(const int* __restrict__ src, int* __restrict__ cnt){
  int e = blockIdx.x*256 + threadIdx.x;
  if(e < NEDGES){
    int s = src[e];
    if((unsigned)s < NNODES) atomicAdd(&cnt[s], 1);
  }
}

// parallel scan: 1024 threads, chunk=20/thread; wave shuffle-scan + LDS cross-wave scan
__global__ __launch_bounds__(1024) void k_scan(int* cnt_cur, int* offs){
  __shared__ int wsum[16];
  int t = threadIdx.x;
  const int chunk = (NNODES + 1023)/1024;   // 20
  int lo = t*chunk, hi = lo+chunk;
  if(lo > NNODES) lo = NNODES;
  if(hi > NNODES) hi = NNODES;
  int s = 0;
  for(int i=lo;i<hi;i++) s += cnt_cur[i];
  int lane = t&63, wv = t>>6;
  int v = s;
  #pragma unroll
  for(int d=1; d<64; d<<=1){
    int u = __shfl_up(v, d);
    if(lane >= d) v += u;
  }
  if(lane==63) wsum[wv] = v;
  __syncthreads();
  if(t==0){
    int run = 0;
    #pragma unroll
    for(int i=0;i<16;i++){ int c = wsum[i]; wsum[i] = run; run += c; }
  }
  __syncthreads();
  int run = wsum[wv] + (v - s);   // exclusive prefix of this thread's chunk
  for(int i=lo;i<hi;i++){
    int c = cnt_cur[i];
    offs[i] = run;
    cnt_cur[i] = run;
    run += c;
  }
  if(t==1023) offs[NNODES] = run;  // thread 1023's chunk is empty -> run == total == NEDGES
}

__global__ __launch_bounds__(256) void k_fill(const int* __restrict__ src,
                                              const int* __restrict__ edst,
                                              const int* __restrict__ species,
                                              int* __restrict__ cur,
                                              int* __restrict__ dsts,
                                              int* __restrict__ sps,
                                              int* __restrict__ pos){
  int e = blockIdx.x*256 + threadIdx.x;
  if(e >= NEDGES) return;
  int s = src[e];
  if((unsigned)s >= NNODES) s = 0;
  int p = atomicAdd(&cur[s], 1);
  if((unsigned)p >= NEDGES) p = 0;
  pos[e] = p;
  int dn = edst[e];
  if((unsigned)dn >= NNODES) dn = 0;
  dsts[p] = dn;
  int sp = species[dn];
  if((unsigned)sp >= 51) sp = 0;
  sps[p] = sp;
}

// ---------------- radial basis -> sorted bf16 rows g_s[p][16] ----------------
__global__ __launch_bounds__(256) void k_G(const void* __restrict__ dist,
                                           const void* __restrict__ sw,
                                           const int* __restrict__ modep,
                                           const int* __restrict__ pos,
                                           uint16_t* __restrict__ gs){
  int e = blockIdx.x*256 + threadIdx.x;
  if(e >= NEDGES) return;
  int md = *modep;
  float r = ldf(dist, e, md);
  float w = ldf(sw, e, md);
  float rinv = 1.0f/r;
  const float sigma = 0.8f/15.0f;
  const float isig  = 15.0f/0.8f;
  uint32_t u[8];
  #pragma unroll
  for(int j=0;j<8;j++){
    float mu0 = 0.2f + sigma*(float)(2*j);
    float mu1 = 0.2f + sigma*(float)(2*j+1);
    float t0 = (rinv-mu0)*isig, t1 = (rinv-mu1)*isig;
    u[j] = packbf(w*__expf(-0.5f*t0*t0), w*__expf(-0.5f*t1*t1));
  }
  int p = pos[e];
  uint4* o = (uint4*)(gs + (size_t)p*16);
  o[0] = make_uint4(u[0],u[1],u[2],u[3]);
  o[1] = make_uint4(u[4],u[5],u[6],u[7]);
}

// ---------------- species tables: ZWs0 fp32, zfb bf16 (51x16) ----------------
__global__ __launch_bounds__(128) void k_spec(const void* __restrict__ Z,
                                              const void* __restrict__ Ws0,
                                              const void* __restrict__ bs0,
                                              const int* __restrict__ modep,
                                              float* __restrict__ ZWs0,
                                              uint16_t* __restrict__ zfb){
  int s = blockIdx.x, d = threadIdx.x;
  int md = *modep;
  float zk[16];
  #pragma unroll
  for(int k=0;k<16;k++) zk[k] = ldf(Z, s*16+k, md);
  float a = ldf(bs0, d, md);
  #pragma unroll
  for(int k=0;k<16;k++) a = fmaf(zk[k], ldf(Ws0, k*128+d, md), a);
  ZWs0[s*128+d] = a;
  if(d < 16) zfb[s*16+d] = f2bf(zk[d]);
}

// ---------------- pack W (Kx128 fp32) into MFMA B-fragment layout, bf16 ----------------
__global__ __launch_bounds__(256) void k_prepB(const float* __restrict__ W, int Ksteps,
                                               uint16_t* __restrict__ Bf){
  int idx = blockIdx.x*256 + threadIdx.x;
  int total = Ksteps*8*64;
  if(idx >= total) return;
  int l = idx & 63, nt = (idx>>6)&7, kk = idx>>9;
  int kbase = kk*32 + (l>>4)*8;
  int dim = nt*16 + (l&15);
  uint32_t u[4];
  #pragma unroll
  for(int t=0;t<4;t++){
    float f0 = W[(size_t)(kbase+2*t)*128 + dim];
    float f1 = W[(size_t)(kbase+2*t+1)*128 + dim];
    u[t] = packbf(f0,f1);
  }
  ((uint4*)Bf)[idx] = make_uint4(u[0],u[1],u[2],u[3]);
}

// pack all 12 onsite 128x128 weights into frags
__global__ __launch_bounds__(256) void k_prepW(const float* __restrict__ conv,
                                               uint16_t* __restrict__ Wf){
  int idx = blockIdx.x*256 + threadIdx.x;
  if(idx >= 12*2048) return;
  int wi = idx>>11, r = idx&2047;
  int l = r & 63, nt = (r>>6)&7, kk = r>>9;
  const float* W = conv + ((wi<6) ? (OFF_WA + wi*16384) : (OFF_WB + (wi-6)*16384));
  int kbase = kk*32 + (l>>4)*8;
  int dim = nt*16 + (l&15);
  uint32_t u[4];
  #pragma unroll
  for(int t=0;t<4;t++){
    float f0 = W[(size_t)(kbase+2*t)*128 + dim];
    float f1 = W[(size_t)(kbase+2*t+1)*128 + dim];
    u[t] = packbf(f0,f1);
  }
  ((uint4*)Wf)[idx] = make_uint4(u[0],u[1],u[2],u[3]);
}

// ---------------- layer-0 fused: MFMA phase A (T0^T = Zf^T @ G) + MFMA GEMM ----------------
// block = 4 waves = one mtile (16 nodes). LDS: 8 ksteps x 64 slots x 8 bf16.
__global__ __launch_bounds__(256) void k_msg0f(const int* __restrict__ offs,
                                               const int* __restrict__ sps,
                                               const uint16_t* __restrict__ gs,
                                               const uint16_t* __restrict__ zfb,
                                               const uint16_t* __restrict__ Bf,
                                               const int* __restrict__ species,
                                               const float* __restrict__ ZWs0,
                                               float* __restrict__ zi){
  __shared__ uint16_t ldsA[8*64*8];   // 8 KB
  int w = threadIdx.x>>6, l = threadIdx.x&63;
  int n0 = blockIdx.x*16;
  int col = l&15, quad = l>>4;
  // phase A: 4 nodes per wave; T0^T[zk][b] = sum_e zfb[sp_e][zk] * g[e][b]
  for(int i=0;i<4;i++){
    int m = w*4 + i;
    int n = n0 + m;
    int beg = offs[n], end = offs[n+1];
    floatx4 acc0 = (floatx4){0.f,0.f,0.f,0.f};
    for(int p0=beg; p0<end; p0+=32){
      int sp[8];
      union { short8 s; uint16_t u[8]; } Bg, Az;
      #pragma unroll
      for(int j=0;j<8;j++){
        int p = p0 + quad*8 + j;
        int pc = p < end ? p : beg;
        sp[j] = sps[pc];
        uint16_t g = gs[(size_t)pc*16 + col];
        Bg.u[j] = (p < end) ? g : (uint16_t)0;
      }
      #pragma unroll
      for(int j=0;j<8;j++)
        Az.u[j] = zfb[sp[j]*16 + col];
      acc0 = __builtin_amdgcn_mfma_f32_16x16x32_bf16(Az.s, Bg.s, acc0, 0,0,0);
    }
    // value (zk = quad*4+reg, b = col): K = b*16 + zk
    int K0 = col*16 + quad*4;
    int kk = K0>>5, qt = (K0>>3)&3, jt = K0&7;
    int slot = kk*64 + ((qt*16 + m) ^ (kk>>2));
    uint32_t lo = packbf(acc0[0], acc0[1]);
    uint32_t hi = packbf(acc0[2], acc0[3]);
    *(uint2*)(&ldsA[slot*8 + jt]) = make_uint2(lo, hi);
  }
  __syncthreads();
  // phase B: wave w -> ntiles w and w+4
  floatx4 acc1 = (floatx4){0.f,0.f,0.f,0.f};
  floatx4 acc2 = (floatx4){0.f,0.f,0.f,0.f};
  const short8* Bp = (const short8*)Bf;
  int nt1 = w, nt2 = w+4;
  #pragma unroll
  for(int kk=0;kk<8;kk++){
    short8 a = *(const short8*)(&ldsA[(kk*64 + (l^(kk>>2)))*8]);
    short8 b1 = Bp[(size_t)(kk*8+nt1)*64 + l];
    short8 b2 = Bp[(size_t)(kk*8+nt2)*64 + l];
    acc1 = __builtin_amdgcn_mfma_f32_16x16x32_bf16(a, b1, acc1, 0,0,0);
    acc2 = __builtin_amdgcn_mfma_f32_16x16x32_bf16(a, b2, acc2, 0,0,0);
  }
  #pragma unroll
  for(int reg=0;reg<4;reg++){
    int node = n0 + quad*4 + reg;
    int sp = species[node];
    if((unsigned)sp >= 51) sp = 0;
    int d1 = nt1*16 + col, d2 = nt2*16 + col;
    zi[(size_t)node*128 + d1] = siluf(acc1[reg] + ZWs0[sp*128 + d1]);
    zi[(size_t)node*128 + d2] = siluf(acc2[reg] + ZWs0[sp*128 + d2]);
  }
}

// ---------------- layer-1 fused: MFMA phase A (T^T = Z^T @ G) + MFMA GEMM (KS1=68) ----------------
// block = 8 waves (512 thr) = one mtile. LDS: 64 ksteps x 64 slots x 8 bf16 = 64 KB.
__global__ __launch_bounds__(512) void k_msg1f(const int* __restrict__ offs,
                                               const int* __restrict__ dsts,
                                               const uint16_t* __restrict__ gs,
                                               const uint16_t* __restrict__ zib,
                                               const uint16_t* __restrict__ Bf,
                                               const float* __restrict__ bias,
                                               float* __restrict__ zacc){
  __shared__ uint16_t ldsA[64*64*8];   // 64 KB
  int w = threadIdx.x>>6, l = threadIdx.x&63;
  int n0 = blockIdx.x*16;
  int col = l&15, quad = l>>4;
  // phase A: 2 nodes per wave
  for(int i=0;i<2;i++){
    int m = w*2 + i;
    int n = n0 + m;
    int beg = offs[n], end = offs[n+1];
    floatx4 acc[8];
    #pragma unroll
    for(int t=0;t<8;t++) acc[t] = (floatx4){0.f,0.f,0.f,0.f};
    for(int p0=beg; p0<end; p0+=32){
      int dn[8];
      union { short8 s; uint16_t u[8]; } Bg;
      #pragma unroll
      for(int j=0;j<8;j++){
        int p = p0 + quad*8 + j;
        int pc = p < end ? p : beg;
        dn[j] = dsts[pc];
        uint16_t g = gs[(size_t)pc*16 + col];
        Bg.u[j] = (p < end) ? g : (uint16_t)0;
      }
      #pragma unroll
      for(int mt=0;mt<8;mt++){
        union { short8 s; uint16_t u[8]; } Az;
        #pragma unroll
        for(int j=0;j<8;j++)
          Az.u[j] = zib[(size_t)dn[j]*128 + mt*16 + col];
        acc[mt] = __builtin_amdgcn_mfma_f32_16x16x32_bf16(Az.s, Bg.s, acc[mt], 0,0,0);
      }
    }
    // value (kz = mt*16 + quad*4+reg, b = col): K = b*128 + kz; reg -> 4 consecutive K
    #pragma unroll
    for(int mt=0;mt<8;mt++){
      int K0 = col*128 + mt*16 + quad*4;
      int kk = K0>>5, qt = (K0>>3)&3, jt = K0&7;
      int slot = kk*64 + ((qt*16 + m) ^ (kk>>2));
      uint32_t lo = packbf(acc[mt][0], acc[mt][1]);
      uint32_t hi = packbf(acc[mt][2], acc[mt][3]);
      *(uint2*)(&ldsA[slot*8 + jt]) = make_uint2(lo, hi);
    }
  }
  __syncthreads();
  // phase B: wave w -> ntile w; ksteps 0..63 from LDS, 64..67 from zib (zself via Ws1 frags)
  floatx4 acc1 = (floatx4){0.f,0.f,0.f,0.f};
  const short8* Bp = (const short8*)Bf;
  for(int kk=0;kk<64;kk++){
    short8 a = *(const short8*)(&ldsA[(kk*64 + (l^(kk>>2)))*8]);
    short8 b1 = Bp[(size_t)(kk*8+w)*64 + l];
    acc1 = __builtin_amdgcn_mfma_f32_16x16x32_bf16(a, b1, acc1, 0,0,0);
  }
  #pragma unroll
  for(int kk=64;kk<KS1;kk++){
    uint4 za = *(const uint4*)(zib + (size_t)(n0+col)*128 + (kk-64)*32 + quad*8);
    union { short8 s; uint4 u; } A; A.u = za;
    short8 b1 = Bp[(size_t)(kk*8+w)*64 + l];
    acc1 = __builtin_amdgcn_mfma_f32_16x16x32_bf16(A.s, b1, acc1, 0,0,0);
  }
  #pragma unroll
  for(int reg=0;reg<4;reg++){
    int node = n0 + quad*4 + reg;
    int d1 = w*16 + col;
    zacc[(size_t)node*128 + d1] = siluf(acc1[reg] + bias[d1]);
  }
}

// ---------------- onsite via MFMA: 3 x (h=silu(z@Wa+ba); z+=h@Wb+bb) ----------------
__global__ __launch_bounds__(128) void k_onsite(float* __restrict__ zi,
                                                const uint16_t* __restrict__ Waf,
                                                const float* __restrict__ ba,
                                                const uint16_t* __restrict__ Wbf,
                                                const float* __restrict__ bb,
                                                void* __restrict__ outb,
                                                long off1, int st1,
                                                long off2, int st2,
                                                const int* __restrict__ modep,
                                                uint16_t* __restrict__ zib){
  __shared__ float zbuf[2][16*132];
  __shared__ float hbuf[2][16*132];
  int w = threadIdx.x>>6, l = threadIdx.x&63;
  int mtile = blockIdx.x*2 + w;
  int n0 = mtile*16;
  int md = *modep;
  float* zb = zbuf[w];
  float* hb = hbuf[w];
  #pragma unroll
  for(int i=0;i<8;i++){
    int flat = (i*64 + l)*4;
    int node = flat>>7, k = flat&127;
    *(float4*)(zb + node*132 + k) = *(const float4*)(zi + (size_t)(n0+node)*128 + k);
  }
  __syncthreads();
  int m = l&15, q = l>>4;
  for(int j=0;j<3;j++){
    const short8* Ba = (const short8*)Waf + (size_t)j*2048 + l;
    floatx4 acc[8];
    #pragma unroll
    for(int t=0;t<8;t++) acc[t] = (floatx4){0.f,0.f,0.f,0.f};
    #pragma unroll
    for(int kk=0;kk<4;kk++){
      const float* zp = zb + m*132 + kk*32 + q*8;
      float4 a0 = *(const float4*)zp, a1 = *(const float4*)(zp+4);
      union { short8 s; uint32_t u[4]; } A;
      A.u[0]=packbf(a0.x,a0.y); A.u[1]=packbf(a0.z,a0.w);
      A.u[2]=packbf(a1.x,a1.y); A.u[3]=packbf(a1.z,a1.w);
      #pragma unroll
      for(int nt=0;nt<8;nt++){
        short8 bfr = Ba[(size_t)(kk*8+nt)*64];
        acc[nt] = __builtin_amdgcn_mfma_f32_16x16x32_bf16(A.s, bfr, acc[nt], 0,0,0);
      }
    }
    #pragma unroll
    for(int nt=0;nt<8;nt++){
      int dim = nt*16 + m;
      float bv = ba[j*128+dim];
      #pragma unroll
      for(int reg=0;reg<4;reg++)
        hb[(q*4+reg)*132 + dim] = siluf(acc[nt][reg] + bv);
    }
    __syncthreads();
    const short8* Bb = (const short8*)Wbf + (size_t)j*2048 + l;
    floatx4 acc2[8];
    #pragma unroll
    for(int t=0;t<8;t++) acc2[t] = (floatx4){0.f,0.f,0.f,0.f};
    #pragma unroll
    for(int kk=0;kk<4;kk++){
      const float* hp = hb + m*132 + kk*32 + q*8;
      float4 a0 = *(const float4*)hp, a1 = *(const float4*)(hp+4);
      union { short8 s; uint32_t u[4]; } A;
      A.u[0]=packbf(a0.x,a0.y); A.u[1]=packbf(a0.z,a0.w);
      A.u[2]=packbf(a1.x,a1.y); A.u[3]=packbf(a1.z,a1.w);
      #pragma unroll
      for(int nt=0;nt<8;nt++){
        short8 bfr = Bb[(size_t)(kk*8+nt)*64];
        acc2[nt] = __builtin_amdgcn_mfma_f32_16x16x32_bf16(A.s, bfr, acc2[nt], 0,0,0);
      }
    }
    __syncthreads();
    #pragma unroll
    for(int nt=0;nt<8;nt++){
      int dim = nt*16 + m;
      float bv = bb[j*128+dim];
      #pragma unroll
      for(int reg=0;reg<4;reg++){
        int idx = (q*4+reg)*132 + dim;
        zb[idx] = zb[idx] + acc2[nt][reg] + bv;
      }
    }
    __syncthreads();
  }
  #pragma unroll
  for(int i=0;i<8;i++){
    int flat = (i*64 + l)*4;
    int node = flat>>7, k = flat&127;
    float4 v = *(float4*)(zb + node*132 + k);
    int n = n0 + node;
    *(float4*)(zi + (size_t)n*128 + k) = v;
    uint2 pv = make_uint2(packbf(v.x,v.y), packbf(v.z,v.w));
    if(zib) *(uint2*)(zib + (size_t)n*128 + k) = pv;
    if(md==1){
      uint16_t* ob = (uint16_t*)outb;
      *(uint2*)(ob + off1 + (long)n*st1 + k) = pv;
      if(off2 >= 0) *(uint2*)(ob + off2 + (long)n*st2 + k) = pv;
    } else {
      float* ob = (float*)outb;
      *(float4*)(ob + off1 + (long)n*st1 + k) = v;
      if(off2 >= 0) *(float4*)(ob + off2 + (long)n*st2 + k) = v;
    }
  }
}

extern "C" void kernel_launch(void* const* d_in, const int* in_sizes, int n_in,
                              void* d_out, int out_size, void* d_ws, size_t ws_size,
                              hipStream_t stream){
  const int* species = (const int*)d_in[0];
  const int* esrc    = (const int*)d_in[1];
  const int* edst    = (const int*)d_in[2];
  const void* dist   = d_in[3];
  const void* swit   = d_in[4];
  const void* Z      = d_in[5];
  const void* Ws0    = d_in[6];
  const void* bs0    = d_in[7];
  const void* V0     = d_in[8];
  const void* Ws1    = d_in[9];
  const void* bs1    = d_in[10];
  const void* V1     = d_in[11];
  const void* Wa     = d_in[12];
  const void* ba     = d_in[13];
  const void* Wb     = d_in[14];
  const void* bb     = d_in[15];

  char* ws = (char*)d_ws;
  size_t off = 0;
  auto alloc = [&](size_t bytes)->void*{ void* p = ws + off; off = (off + bytes + 255) & ~(size_t)255; return p; };
  int*      offs = (int*)     alloc((size_t)(NNODES+1)*4);
  int*      cur  = (int*)     alloc((size_t)NNODES*4);
  int*      pos  = (int*)     alloc((size_t)NEDGES*4);
  int*      dsts = (int*)     alloc((size_t)NEDGES*4);
  int*      sps  = (int*)     alloc((size_t)NEDGES*4);
  uint16_t* gs   = (uint16_t*)alloc((size_t)NEDGES*16*2);      // 12.8 MB
  float*    zi   = (float*)   alloc((size_t)NNODES*128*4);     // 10.24 MB
  float*    zacc = (float*)   alloc((size_t)NNODES*128*4);     // 10.24 MB
  uint16_t* zib  = (uint16_t*)alloc((size_t)NNODES*128*2);     // 5.12 MB
  float*    ZWs0 = (float*)   alloc((size_t)51*128*4);
  uint16_t* zfb  = (uint16_t*)alloc((size_t)51*16*2);
  float*    conv = (float*)   alloc((size_t)N_CONV*4);         // 2.04 MB
  uint16_t* Bf0  = (uint16_t*)alloc((size_t)8*8*64*8*2);       // 64 KB
  uint16_t* Bf1  = (uint16_t*)alloc((size_t)KS1*8*64*8*2);     // 557 KB
  uint16_t* Wfr  = (uint16_t*)alloc((size_t)12*16384*2);       // 384 KB
  int*      mode = (int*)     alloc(256);

  const int EB = (NEDGES+255)/256;
  hipMemsetAsync(cur, 0, NNODES*4, stream);
  k_probe<<<1,64,0,stream>>>(dist, mode);
  k_conv <<<(N_CONV+255)/256,256,0,stream>>>(V0, Ws1, bs1, V1, Wa, ba, Wb, bb, mode, conv);
  k_hist <<<EB,256,0,stream>>>(esrc, cur);
  k_scan <<<1,1024,0,stream>>>(cur, offs);
  k_fill <<<EB,256,0,stream>>>(esrc, edst, species, cur, dsts, sps, pos);
  k_G    <<<EB,256,0,stream>>>(dist, swit, mode, pos, gs);
  k_spec <<<51,128,0,stream>>>(Z, Ws0, bs0, mode, ZWs0, zfb);
  k_prepB<<<(8*8*64+255)/256,256,0,stream>>>(conv+OFF_V0, 8,  Bf0);
  k_prepB<<<(64*8*64+255)/256,256,0,stream>>>(conv+OFF_V1, 64, Bf1);
  k_prepB<<<(4*8*64+255)/256,256,0,stream>>>(conv+OFF_WS1, 4, Bf1 + (size_t)64*8*64*8);
  k_prepW<<<(12*2048+255)/256,256,0,stream>>>(conv, Wfr);

  const long ZIS = (long)NNODES*128;
  uint16_t* WaF0 = Wfr;
  uint16_t* WaF1 = Wfr + (size_t)3*16384;
  uint16_t* WbF0 = Wfr + (size_t)6*16384;
  uint16_t* WbF1 = Wfr + (size_t)9*16384;

  // layer 0 (fused MFMA scatter+GEMM)
  k_msg0f<<<MTILES,256,0,stream>>>(offs, sps, gs, zfb, Bf0, species, ZWs0, zi);
  k_onsite<<<MTILES/2,128,0,stream>>>(zi, WaF0, conv+OFF_BA, WbF0, conv+OFF_BB,
                                      d_out, ZIS, 256, (long)-1, 0, mode, zib);

  // layer 1 (fused MFMA scatter+GEMM incl. zself ksteps)
  k_msg1f<<<MTILES,512,0,stream>>>(offs, dsts, gs, zib, Bf1, conv+OFF_BS1, zacc);
  k_onsite<<<MTILES/2,128,0,stream>>>(zacc, WaF1, conv+OFF_BA+384, WbF1, conv+OFF_BB+384,
                                      d_out, ZIS+128, 256, (long)0, 128, mode, (uint16_t*)nullptr);
}

// Round 10
// 313.457 us; speedup vs baseline: 1.8081x; 1.3122x over previous
//
#include <hip/hip_runtime.h>
#include <stdint.h>

#define NNODES 20000
#define NEDGES 400000
#define MTILES 1250   // 20000/16
#define KS1 68        // layer-1 msg GEMM ksteps: 64 (T@V1) + 4 (zi@Ws1)

typedef __attribute__((ext_vector_type(8))) short short8;
typedef __attribute__((ext_vector_type(4))) float floatx4;

__device__ __forceinline__ float bf2f(uint16_t u){ return __uint_as_float(((uint32_t)u)<<16); }
__device__ __forceinline__ uint16_t f2bf(float f){
  uint32_t x = __float_as_uint(f);
  x += 0x7FFFu + ((x>>16)&1u);
  return (uint16_t)(x>>16);
}
__device__ __forceinline__ uint32_t packbf(float a, float b){
  return (uint32_t)f2bf(a) | ((uint32_t)f2bf(b)<<16);
}
__device__ __forceinline__ float siluf(float x){ return x/(1.0f+__expf(-x)); }
__device__ __forceinline__ float ldf(const void* p, int i, int md){
  return (md==1) ? bf2f(((const uint16_t*)p)[i]) : ((const float*)p)[i];
}

// converted-weights layout (float elements within conv buffer)
#define OFF_V0   0
#define N_V0     32768
#define OFF_WS1  32768
#define N_WS1    16384
#define OFF_BS1  49152
#define N_BS1    128
#define OFF_V1   49280
#define N_V1     262144
#define OFF_WA   311424
#define N_WA     98304
#define OFF_BA   409728
#define N_BA     768
#define OFF_WB   410496
#define N_WB     98304
#define OFF_BB   508800
#define N_BB     768
#define N_CONV   509568

// ---------------- dtype probe ----------------
__global__ void k_probe(const void* dist, int* mode){
  if(threadIdx.x != 0 || blockIdx.x != 0) return;
  const float* f = (const float*)dist;
  const uint16_t* h = (const uint16_t*)dist;
  int okf = 1, okb = 1;
  for(int i=0;i<256;i++){
    float a = f[i];       okf &= (a >= 0.7f) & (a <= 5.1f);
    float b = bf2f(h[i]); okb &= (b >= 0.7f) & (b <= 5.1f);
  }
  *mode = okb ? 1 : (okf ? 0 : 1);
}

// ---------------- convert all weight tensors to fp32 ----------------
__global__ __launch_bounds__(256) void k_conv(const void* s0,const void* s1,const void* s2,const void* s3,
                                              const void* s4,const void* s5,const void* s6,const void* s7,
                                              const int* __restrict__ modep, float* __restrict__ dst){
  int md = *modep;
  int i = blockIdx.x*256 + threadIdx.x;
  if(i >= N_CONV) return;
  const void* src; int t = i;
  if(t < N_V0){src=s0;}
  else if((t-=N_V0) < N_WS1){src=s1;}
  else if((t-=N_WS1) < N_BS1){src=s2;}
  else if((t-=N_BS1) < N_V1){src=s3;}
  else if((t-=N_V1) < N_WA){src=s4;}
  else if((t-=N_WA) < N_BA){src=s5;}
  else if((t-=N_BA) < N_WB){src=s6;}
  else {t-=N_WB; src=s7;}
  dst[i] = ldf(src, t, md);
}

// ---------------- CSR build ----------------
__global__ __launch_bounds__(256) void k_hist(const int* __restrict__ src, int* __restrict__ cnt){
  int e = blockIdx.x*256 + threadIdx.x;
  if(e < NEDGES){
    int s = src[e];
    if((unsigned)s < NNODES) atomicAdd(&cnt[s], 1);
  }
}

// parallel scan: 1024 threads, chunk=20/thread; wave shuffle-scan + LDS cross-wave scan
__global__ __launch_bounds__(1024) void k_scan(int* cnt_cur, int* offs){
  __shared__ int wsum[16];
  int t = threadIdx.x;
  const int chunk = (NNODES + 1023)/1024;   // 20
  int lo = t*chunk, hi = lo+chunk;
  if(lo > NNODES) lo = NNODES;
  if(hi > NNODES) hi = NNODES;
  int s = 0;
  for(int i=lo;i<hi;i++) s += cnt_cur[i];
  int lane = t&63, wv = t>>6;
  int v = s;
  #pragma unroll
  for(int d=1; d<64; d<<=1){
    int u = __shfl_up(v, d);
    if(lane >= d) v += u;
  }
  if(lane==63) wsum[wv] = v;
  __syncthreads();
  if(t==0){
    int run = 0;
    #pragma unroll
    for(int i=0;i<16;i++){ int c = wsum[i]; wsum[i] = run; run += c; }
  }
  __syncthreads();
  int run = wsum[wv] + (v - s);   // exclusive prefix of this thread's chunk
  for(int i=lo;i<hi;i++){
    int c = cnt_cur[i];
    offs[i] = run;
    cnt_cur[i] = run;
    run += c;
  }
  if(t==1023) offs[NNODES] = run;  // thread 1023's chunk is empty -> run == total == NEDGES
}

__global__ __launch_bounds__(256) void k_fill(const int* __restrict__ src,
                                              const int* __restrict__ edst,
                                              const int* __restrict__ species,
                                              int* __restrict__ cur,
                                              int* __restrict__ dsts,
                                              int* __restrict__ sps,
                                              int* __restrict__ pos){
  int e = blockIdx.x*256 + threadIdx.x;
  if(e >= NEDGES) return;
  int s = src[e];
  if((unsigned)s >= NNODES) s = 0;
  int p = atomicAdd(&cur[s], 1);
  if((unsigned)p >= NEDGES) p = 0;
  pos[e] = p;
  int dn = edst[e];
  if((unsigned)dn >= NNODES) dn = 0;
  dsts[p] = dn;
  int sp = species[dn];
  if((unsigned)sp >= 51) sp = 0;
  sps[p] = sp;
}

// ---------------- radial basis -> sorted bf16 rows g_s[p][16] ----------------
__global__ __launch_bounds__(256) void k_G(const void* __restrict__ dist,
                                           const void* __restrict__ sw,
                                           const int* __restrict__ modep,
                                           const int* __restrict__ pos,
                                           uint16_t* __restrict__ gs){
  int e = blockIdx.x*256 + threadIdx.x;
  if(e >= NEDGES) return;
  int md = *modep;
  float r = ldf(dist, e, md);
  float w = ldf(sw, e, md);
  float rinv = 1.0f/r;
  const float sigma = 0.8f/15.0f;
  const float isig  = 15.0f/0.8f;
  uint32_t u[8];
  #pragma unroll
  for(int j=0;j<8;j++){
    float mu0 = 0.2f + sigma*(float)(2*j);
    float mu1 = 0.2f + sigma*(float)(2*j+1);
    float t0 = (rinv-mu0)*isig, t1 = (rinv-mu1)*isig;
    u[j] = packbf(w*__expf(-0.5f*t0*t0), w*__expf(-0.5f*t1*t1));
  }
  int p = pos[e];
  uint4* o = (uint4*)(gs + (size_t)p*16);
  o[0] = make_uint4(u[0],u[1],u[2],u[3]);
  o[1] = make_uint4(u[4],u[5],u[6],u[7]);
}

// ---------------- species tables: ZWs0 fp32, zfb bf16 (51x16) ----------------
__global__ __launch_bounds__(128) void k_spec(const void* __restrict__ Z,
                                              const void* __restrict__ Ws0,
                                              const void* __restrict__ bs0,
                                              const int* __restrict__ modep,
                                              float* __restrict__ ZWs0,
                                              uint16_t* __restrict__ zfb){
  int s = blockIdx.x, d = threadIdx.x;
  int md = *modep;
  float zk[16];
  #pragma unroll
  for(int k=0;k<16;k++) zk[k] = ldf(Z, s*16+k, md);
  float a = ldf(bs0, d, md);
  #pragma unroll
  for(int k=0;k<16;k++) a = fmaf(zk[k], ldf(Ws0, k*128+d, md), a);
  ZWs0[s*128+d] = a;
  if(d < 16) zfb[s*16+d] = f2bf(zk[d]);
}

// ---------------- pack W (Kx128 fp32) into MFMA B-fragment layout, bf16 ----------------
__global__ __launch_bounds__(256) void k_prepB(const float* __restrict__ W, int Ksteps,
                                               uint16_t* __restrict__ Bf){
  int idx = blockIdx.x*256 + threadIdx.x;
  int total = Ksteps*8*64;
  if(idx >= total) return;
  int l = idx & 63, nt = (idx>>6)&7, kk = idx>>9;
  int kbase = kk*32 + (l>>4)*8;
  int dim = nt*16 + (l&15);
  uint32_t u[4];
  #pragma unroll
  for(int t=0;t<4;t++){
    float f0 = W[(size_t)(kbase+2*t)*128 + dim];
    float f1 = W[(size_t)(kbase+2*t+1)*128 + dim];
    u[t] = packbf(f0,f1);
  }
  ((uint4*)Bf)[idx] = make_uint4(u[0],u[1],u[2],u[3]);
}

// pack all 12 onsite 128x128 weights into frags
__global__ __launch_bounds__(256) void k_prepW(const float* __restrict__ conv,
                                               uint16_t* __restrict__ Wf){
  int idx = blockIdx.x*256 + threadIdx.x;
  if(idx >= 12*2048) return;
  int wi = idx>>11, r = idx&2047;
  int l = r & 63, nt = (r>>6)&7, kk = r>>9;
  const float* W = conv + ((wi<6) ? (OFF_WA + wi*16384) : (OFF_WB + (wi-6)*16384));
  int kbase = kk*32 + (l>>4)*8;
  int dim = nt*16 + (l&15);
  uint32_t u[4];
  #pragma unroll
  for(int t=0;t<4;t++){
    float f0 = W[(size_t)(kbase+2*t)*128 + dim];
    float f1 = W[(size_t)(kbase+2*t+1)*128 + dim];
    u[t] = packbf(f0,f1);
  }
  ((uint4*)Wf)[idx] = make_uint4(u[0],u[1],u[2],u[3]);
}

// ---------------- layer-0 fused: MFMA phase A (T0^T = Zf^T @ G) + MFMA GEMM ----------------
// block = 4 waves = one mtile (16 nodes). LDS: 8 ksteps x 64 slots x 8 bf16.
__global__ __launch_bounds__(256) void k_msg0f(const int* __restrict__ offs,
                                               const int* __restrict__ sps,
                                               const uint16_t* __restrict__ gs,
                                               const uint16_t* __restrict__ zfb,
                                               const uint16_t* __restrict__ Bf,
                                               const int* __restrict__ species,
                                               const float* __restrict__ ZWs0,
                                               float* __restrict__ zi){
  __shared__ uint16_t ldsA[8*64*8];   // 8 KB
  int w = threadIdx.x>>6, l = threadIdx.x&63;
  int n0 = blockIdx.x*16;
  int col = l&15, quad = l>>4;
  // phase A: 4 nodes per wave; T0^T[zk][b] = sum_e zfb[sp_e][zk] * g[e][b]
  for(int i=0;i<4;i++){
    int m = w*4 + i;
    int n = n0 + m;
    int beg = offs[n], end = offs[n+1];
    floatx4 acc0 = (floatx4){0.f,0.f,0.f,0.f};
    for(int p0=beg; p0<end; p0+=32){
      int sp[8];
      union { short8 s; uint16_t u[8]; } Bg, Az;
      #pragma unroll
      for(int j=0;j<8;j++){
        int p = p0 + quad*8 + j;
        int pc = p < end ? p : beg;
        sp[j] = sps[pc];
        uint16_t g = gs[(size_t)pc*16 + col];
        Bg.u[j] = (p < end) ? g : (uint16_t)0;
      }
      #pragma unroll
      for(int j=0;j<8;j++)
        Az.u[j] = zfb[sp[j]*16 + col];
      acc0 = __builtin_amdgcn_mfma_f32_16x16x32_bf16(Az.s, Bg.s, acc0, 0,0,0);
    }
    // value (zk = quad*4+reg, b = col): K = b*16 + zk
    int K0 = col*16 + quad*4;
    int kk = K0>>5, qt = (K0>>3)&3, jt = K0&7;
    int slot = kk*64 + ((qt*16 + m) ^ (kk>>2));
    uint32_t lo = packbf(acc0[0], acc0[1]);
    uint32_t hi = packbf(acc0[2], acc0[3]);
    *(uint2*)(&ldsA[slot*8 + jt]) = make_uint2(lo, hi);
  }
  __syncthreads();
  // phase B: wave w -> ntiles w and w+4
  floatx4 acc1 = (floatx4){0.f,0.f,0.f,0.f};
  floatx4 acc2 = (floatx4){0.f,0.f,0.f,0.f};
  const short8* Bp = (const short8*)Bf;
  int nt1 = w, nt2 = w+4;
  #pragma unroll
  for(int kk=0;kk<8;kk++){
    short8 a = *(const short8*)(&ldsA[(kk*64 + (l^(kk>>2)))*8]);
    short8 b1 = Bp[(size_t)(kk*8+nt1)*64 + l];
    short8 b2 = Bp[(size_t)(kk*8+nt2)*64 + l];
    acc1 = __builtin_amdgcn_mfma_f32_16x16x32_bf16(a, b1, acc1, 0,0,0);
    acc2 = __builtin_amdgcn_mfma_f32_16x16x32_bf16(a, b2, acc2, 0,0,0);
  }
  #pragma unroll
  for(int reg=0;reg<4;reg++){
    int node = n0 + quad*4 + reg;
    int sp = species[node];
    if((unsigned)sp >= 51) sp = 0;
    int d1 = nt1*16 + col, d2 = nt2*16 + col;
    zi[(size_t)node*128 + d1] = siluf(acc1[reg] + ZWs0[sp*128 + d1]);
    zi[(size_t)node*128 + d2] = siluf(acc2[reg] + ZWs0[sp*128 + d2]);
  }
}

// ---------------- layer-1 fused: MFMA phase A (T^T = Z^T @ G) + MFMA GEMM (KS1=68) ----------------
// block = 8 waves (512 thr) = one mtile. LDS: 64 ksteps x 64 slots x 8 bf16 = 64 KB.
__global__ __launch_bounds__(512) void k_msg1f(const int* __restrict__ offs,
                                               const int* __restrict__ dsts,
                                               const uint16_t* __restrict__ gs,
                                               const uint16_t* __restrict__ zib,
                                               const uint16_t* __restrict__ Bf,
                                               const float* __restrict__ bias,
                                               float* __restrict__ zacc){
  __shared__ uint16_t ldsA[64*64*8];   // 64 KB
  int w = threadIdx.x>>6, l = threadIdx.x&63;
  int n0 = blockIdx.x*16;
  int col = l&15, quad = l>>4;
  // phase A: 2 nodes per wave
  for(int i=0;i<2;i++){
    int m = w*2 + i;
    int n = n0 + m;
    int beg = offs[n], end = offs[n+1];
    floatx4 acc[8];
    #pragma unroll
    for(int t=0;t<8;t++) acc[t] = (floatx4){0.f,0.f,0.f,0.f};
    for(int p0=beg; p0<end; p0+=32){
      int dn[8];
      union { short8 s; uint16_t u[8]; } Bg;
      #pragma unroll
      for(int j=0;j<8;j++){
        int p = p0 + quad*8 + j;
        int pc = p < end ? p : beg;
        dn[j] = dsts[pc];
        uint16_t g = gs[(size_t)pc*16 + col];
        Bg.u[j] = (p < end) ? g : (uint16_t)0;
      }
      #pragma unroll
      for(int mt=0;mt<8;mt++){
        union { short8 s; uint16_t u[8]; } Az;
        #pragma unroll
        for(int j=0;j<8;j++)
          Az.u[j] = zib[(size_t)dn[j]*128 + mt*16 + col];
        acc[mt] = __builtin_amdgcn_mfma_f32_16x16x32_bf16(Az.s, Bg.s, acc[mt], 0,0,0);
      }
    }
    // value (kz = mt*16 + quad*4+reg, b = col): K = b*128 + kz; reg -> 4 consecutive K
    #pragma unroll
    for(int mt=0;mt<8;mt++){
      int K0 = col*128 + mt*16 + quad*4;
      int kk = K0>>5, qt = (K0>>3)&3, jt = K0&7;
      int slot = kk*64 + ((qt*16 + m) ^ (kk>>2));
      uint32_t lo = packbf(acc[mt][0], acc[mt][1]);
      uint32_t hi = packbf(acc[mt][2], acc[mt][3]);
      *(uint2*)(&ldsA[slot*8 + jt]) = make_uint2(lo, hi);
    }
  }
  __syncthreads();
  // phase B: wave w -> ntile w; ksteps 0..63 from LDS, 64..67 from zib (zself via Ws1 frags)
  floatx4 acc1 = (floatx4){0.f,0.f,0.f,0.f};
  const short8* Bp = (const short8*)Bf;
  for(int kk=0;kk<64;kk++){
    short8 a = *(const short8*)(&ldsA[(kk*64 + (l^(kk>>2)))*8]);
    short8 b1 = Bp[(size_t)(kk*8+w)*64 + l];
    acc1 = __builtin_amdgcn_mfma_f32_16x16x32_bf16(a, b1, acc1, 0,0,0);
  }
  #pragma unroll
  for(int kk=64;kk<KS1;kk++){
    uint4 za = *(const uint4*)(zib + (size_t)(n0+col)*128 + (kk-64)*32 + quad*8);
    union { short8 s; uint4 u; } A; A.u = za;
    short8 b1 = Bp[(size_t)(kk*8+w)*64 + l];
    acc1 = __builtin_amdgcn_mfma_f32_16x16x32_bf16(A.s, b1, acc1, 0,0,0);
  }
  #pragma unroll
  for(int reg=0;reg<4;reg++){
    int node = n0 + quad*4 + reg;
    int d1 = w*16 + col;
    zacc[(size_t)node*128 + d1] = siluf(acc1[reg] + bias[d1]);
  }
}

// ---------------- onsite via MFMA: 3 x (h=silu(z@Wa+ba); z+=h@Wb+bb) ----------------
// block = 256 thr = 4 waves = one mtile; each wave computes 2 n-tiles per GEMM stage.
__global__ __launch_bounds__(256) void k_onsite(float* __restrict__ zi,
                                                const uint16_t* __restrict__ Waf,
                                                const float* __restrict__ ba,
                                                const uint16_t* __restrict__ Wbf,
                                                const float* __restrict__ bb,
                                                void* __restrict__ outb,
                                                long off1, int st1,
                                                long off2, int st2,
                                                const int* __restrict__ modep,
                                                uint16_t* __restrict__ zib){
  __shared__ float zb[16*132];
  __shared__ float hb[16*132];
  int w = threadIdx.x>>6, l = threadIdx.x&63;
  int mtile = blockIdx.x;
  int n0 = mtile*16;
  int md = *modep;
  #pragma unroll
  for(int i=0;i<2;i++){
    int flat = (i*256 + threadIdx.x)*4;
    int node = flat>>7, k = flat&127;
    *(float4*)(zb + node*132 + k) = *(const float4*)(zi + (size_t)(n0+node)*128 + k);
  }
  __syncthreads();
  int m = l&15, q = l>>4;
  for(int j=0;j<3;j++){
    // stage 1: h = silu(z@Wa + ba); wave w -> ntiles 2w, 2w+1
    const short8* Ba = (const short8*)Waf + (size_t)j*2048 + l;
    floatx4 acc[2];
    acc[0] = (floatx4){0.f,0.f,0.f,0.f};
    acc[1] = (floatx4){0.f,0.f,0.f,0.f};
    #pragma unroll
    for(int kk=0;kk<4;kk++){
      const float* zp = zb + m*132 + kk*32 + q*8;
      float4 a0 = *(const float4*)zp, a1 = *(const float4*)(zp+4);
      union { short8 s; uint32_t u[4]; } A;
      A.u[0]=packbf(a0.x,a0.y); A.u[1]=packbf(a0.z,a0.w);
      A.u[2]=packbf(a1.x,a1.y); A.u[3]=packbf(a1.z,a1.w);
      #pragma unroll
      for(int t=0;t<2;t++){
        short8 bfr = Ba[(size_t)(kk*8 + w*2+t)*64];
        acc[t] = __builtin_amdgcn_mfma_f32_16x16x32_bf16(A.s, bfr, acc[t], 0,0,0);
      }
    }
    #pragma unroll
    for(int t=0;t<2;t++){
      int dim = (w*2+t)*16 + m;
      float bv = ba[j*128+dim];
      #pragma unroll
      for(int reg=0;reg<4;reg++)
        hb[(q*4+reg)*132 + dim] = siluf(acc[t][reg] + bv);
    }
    __syncthreads();
    // stage 2: z += h@Wb + bb; wave w -> ntiles 2w, 2w+1
    const short8* Bb = (const short8*)Wbf + (size_t)j*2048 + l;
    floatx4 acc2[2];
    acc2[0] = (floatx4){0.f,0.f,0.f,0.f};
    acc2[1] = (floatx4){0.f,0.f,0.f,0.f};
    #pragma unroll
    for(int kk=0;kk<4;kk++){
      const float* hp = hb + m*132 + kk*32 + q*8;
      float4 a0 = *(const float4*)hp, a1 = *(const float4*)(hp+4);
      union { short8 s; uint32_t u[4]; } A;
      A.u[0]=packbf(a0.x,a0.y); A.u[1]=packbf(a0.z,a0.w);
      A.u[2]=packbf(a1.x,a1.y); A.u[3]=packbf(a1.z,a1.w);
      #pragma unroll
      for(int t=0;t<2;t++){
        short8 bfr = Bb[(size_t)(kk*8 + w*2+t)*64];
        acc2[t] = __builtin_amdgcn_mfma_f32_16x16x32_bf16(A.s, bfr, acc2[t], 0,0,0);
      }
    }
    #pragma unroll
    for(int t=0;t<2;t++){
      int dim = (w*2+t)*16 + m;
      float bv = bb[j*128+dim];
      #pragma unroll
      for(int reg=0;reg<4;reg++){
        int idx = (q*4+reg)*132 + dim;
        zb[idx] = zb[idx] + acc2[t][reg] + bv;
      }
    }
    __syncthreads();
  }
  #pragma unroll
  for(int i=0;i<2;i++){
    int flat = (i*256 + threadIdx.x)*4;
    int node = flat>>7, k = flat&127;
    float4 v = *(float4*)(zb + node*132 + k);
    int n = n0 + node;
    *(float4*)(zi + (size_t)n*128 + k) = v;
    uint2 pv = make_uint2(packbf(v.x,v.y), packbf(v.z,v.w));
    if(zib) *(uint2*)(zib + (size_t)n*128 + k) = pv;
    if(md==1){
      uint16_t* ob = (uint16_t*)outb;
      *(uint2*)(ob + off1 + (long)n*st1 + k) = pv;
      if(off2 >= 0) *(uint2*)(ob + off2 + (long)n*st2 + k) = pv;
    } else {
      float* ob = (float*)outb;
      *(float4*)(ob + off1 + (long)n*st1 + k) = v;
      if(off2 >= 0) *(float4*)(ob + off2 + (long)n*st2 + k) = v;
    }
  }
}

extern "C" void kernel_launch(void* const* d_in, const int* in_sizes, int n_in,
                              void* d_out, int out_size, void* d_ws, size_t ws_size,
                              hipStream_t stream){
  const int* species = (const int*)d_in[0];
  const int* esrc    = (const int*)d_in[1];
  const int* edst    = (const int*)d_in[2];
  const void* dist   = d_in[3];
  const void* swit   = d_in[4];
  const void* Z      = d_in[5];
  const void* Ws0    = d_in[6];
  const void* bs0    = d_in[7];
  const void* V0     = d_in[8];
  const void* Ws1    = d_in[9];
  const void* bs1    = d_in[10];
  const void* V1     = d_in[11];
  const void* Wa     = d_in[12];
  const void* ba     = d_in[13];
  const void* Wb     = d_in[14];
  const void* bb     = d_in[15];

  char* ws = (char*)d_ws;
  size_t off = 0;
  auto alloc = [&](size_t bytes)->void*{ void* p = ws + off; off = (off + bytes + 255) & ~(size_t)255; return p; };
  int*      offs = (int*)     alloc((size_t)(NNODES+1)*4);
  int*      cur  = (int*)     alloc((size_t)NNODES*4);
  int*      pos  = (int*)     alloc((size_t)NEDGES*4);
  int*      dsts = (int*)     alloc((size_t)NEDGES*4);
  int*      sps  = (int*)     alloc((size_t)NEDGES*4);
  uint16_t* gs   = (uint16_t*)alloc((size_t)NEDGES*16*2);      // 12.8 MB
  float*    zi   = (float*)   alloc((size_t)NNODES*128*4);     // 10.24 MB
  float*    zacc = (float*)   alloc((size_t)NNODES*128*4);     // 10.24 MB
  uint16_t* zib  = (uint16_t*)alloc((size_t)NNODES*128*2);     // 5.12 MB
  float*    ZWs0 = (float*)   alloc((size_t)51*128*4);
  uint16_t* zfb  = (uint16_t*)alloc((size_t)51*16*2);
  float*    conv = (float*)   alloc((size_t)N_CONV*4);         // 2.04 MB
  uint16_t* Bf0  = (uint16_t*)alloc((size_t)8*8*64*8*2);       // 64 KB
  uint16_t* Bf1  = (uint16_t*)alloc((size_t)KS1*8*64*8*2);     // 557 KB
  uint16_t* Wfr  = (uint16_t*)alloc((size_t)12*16384*2);       // 384 KB
  int*      mode = (int*)     alloc(256);

  const int EB = (NEDGES+255)/256;
  hipMemsetAsync(cur, 0, NNODES*4, stream);
  k_probe<<<1,64,0,stream>>>(dist, mode);
  k_conv <<<(N_CONV+255)/256,256,0,stream>>>(V0, Ws1, bs1, V1, Wa, ba, Wb, bb, mode, conv);
  k_hist <<<EB,256,0,stream>>>(esrc, cur);
  k_scan <<<1,1024,0,stream>>>(cur, offs);
  k_fill <<<EB,256,0,stream>>>(esrc, edst, species, cur, dsts, sps, pos);
  k_G    <<<EB,256,0,stream>>>(dist, swit, mode, pos, gs);
  k_spec <<<51,128,0,stream>>>(Z, Ws0, bs0, mode, ZWs0, zfb);
  k_prepB<<<(8*8*64+255)/256,256,0,stream>>>(conv+OFF_V0, 8,  Bf0);
  k_prepB<<<(64*8*64+255)/256,256,0,stream>>>(conv+OFF_V1, 64, Bf1);
  k_prepB<<<(4*8*64+255)/256,256,0,stream>>>(conv+OFF_WS1, 4, Bf1 + (size_t)64*8*64*8);
  k_prepW<<<(12*2048+255)/256,256,0,stream>>>(conv, Wfr);

  const long ZIS = (long)NNODES*128;
  uint16_t* WaF0 = Wfr;
  uint16_t* WaF1 = Wfr + (size_t)3*16384;
  uint16_t* WbF0 = Wfr + (size_t)6*16384;
  uint16_t* WbF1 = Wfr + (size_t)9*16384;

  // layer 0 (fused MFMA scatter+GEMM)
  k_msg0f<<<MTILES,256,0,stream>>>(offs, sps, gs, zfb, Bf0, species, ZWs0, zi);
  k_onsite<<<MTILES,256,0,stream>>>(zi, WaF0, conv+OFF_BA, WbF0, conv+OFF_BB,
                                    d_out, ZIS, 256, (long)-1, 0, mode, zib);

  // layer 1 (fused MFMA scatter+GEMM incl. zself ksteps)
  k_msg1f<<<MTILES,512,0,stream>>>(offs, dsts, gs, zib, Bf1, conv+OFF_BS1, zacc);
  k_onsite<<<MTILES,256,0,stream>>>(zacc, WaF1, conv+OFF_BA+384, WbF1, conv+OFF_BB+384,
                                    d_out, ZIS+128, 256, (long)0, 128, mode, (uint16_t*)nullptr);
}

// Round 11
// 304.345 us; speedup vs baseline: 1.8623x; 1.0299x over previous
//
#include <hip/hip_runtime.h>
#include <stdint.h>

#define NNODES 20000
#define NEDGES 400000
#define MTILES 1250   // 20000/16
#define KS1 68        // layer-1 msg GEMM ksteps: 64 (T@V1) + 4 (zi@Ws1)

typedef __attribute__((ext_vector_type(8))) short short8;
typedef __attribute__((ext_vector_type(4))) float floatx4;

__device__ __forceinline__ float bf2f(uint16_t u){ return __uint_as_float(((uint32_t)u)<<16); }
__device__ __forceinline__ uint16_t f2bf(float f){
  uint32_t x = __float_as_uint(f);
  x += 0x7FFFu + ((x>>16)&1u);
  return (uint16_t)(x>>16);
}
__device__ __forceinline__ uint32_t packbf(float a, float b){
  return (uint32_t)f2bf(a) | ((uint32_t)f2bf(b)<<16);
}
__device__ __forceinline__ float siluf(float x){ return x/(1.0f+__expf(-x)); }
__device__ __forceinline__ float ldf(const void* p, int i, int md){
  return (md==1) ? bf2f(((const uint16_t*)p)[i]) : ((const float*)p)[i];
}

// converted-weights layout (float elements within conv buffer)
#define OFF_V0   0
#define N_V0     32768
#define OFF_WS1  32768
#define N_WS1    16384
#define OFF_BS1  49152
#define N_BS1    128
#define OFF_V1   49280
#define N_V1     262144
#define OFF_WA   311424
#define N_WA     98304
#define OFF_BA   409728
#define N_BA     768
#define OFF_WB   410496
#define N_WB     98304
#define OFF_BB   508800
#define N_BB     768
#define N_CONV   509568

// ---------------- dtype probe ----------------
__global__ void k_probe(const void* dist, int* mode){
  if(threadIdx.x != 0 || blockIdx.x != 0) return;
  const float* f = (const float*)dist;
  const uint16_t* h = (const uint16_t*)dist;
  int okf = 1, okb = 1;
  for(int i=0;i<256;i++){
    float a = f[i];       okf &= (a >= 0.7f) & (a <= 5.1f);
    float b = bf2f(h[i]); okb &= (b >= 0.7f) & (b <= 5.1f);
  }
  *mode = okb ? 1 : (okf ? 0 : 1);
}

// ---------------- convert all weight tensors to fp32 ----------------
__global__ __launch_bounds__(256) void k_conv(const void* s0,const void* s1,const void* s2,const void* s3,
                                              const void* s4,const void* s5,const void* s6,const void* s7,
                                              const int* __restrict__ modep, float* __restrict__ dst){
  int md = *modep;
  int i = blockIdx.x*256 + threadIdx.x;
  if(i >= N_CONV) return;
  const void* src; int t = i;
  if(t < N_V0){src=s0;}
  else if((t-=N_V0) < N_WS1){src=s1;}
  else if((t-=N_WS1) < N_BS1){src=s2;}
  else if((t-=N_BS1) < N_V1){src=s3;}
  else if((t-=N_V1) < N_WA){src=s4;}
  else if((t-=N_WA) < N_BA){src=s5;}
  else if((t-=N_BA) < N_WB){src=s6;}
  else {t-=N_WB; src=s7;}
  dst[i] = ldf(src, t, md);
}

// ---------------- CSR build ----------------
__global__ __launch_bounds__(256) void k_hist(const int* __restrict__ src, int* __restrict__ cnt){
  int e = blockIdx.x*256 + threadIdx.x;
  if(e < NEDGES){
    int s = src[e];
    if((unsigned)s < NNODES) atomicAdd(&cnt[s], 1);
  }
}

// parallel scan: 1024 threads, chunk=20/thread; wave shuffle-scan + LDS cross-wave scan
__global__ __launch_bounds__(1024) void k_scan(int* cnt_cur, int* offs){
  __shared__ int wsum[16];
  int t = threadIdx.x;
  const int chunk = (NNODES + 1023)/1024;   // 20
  int lo = t*chunk, hi = lo+chunk;
  if(lo > NNODES) lo = NNODES;
  if(hi > NNODES) hi = NNODES;
  int s = 0;
  for(int i=lo;i<hi;i++) s += cnt_cur[i];
  int lane = t&63, wv = t>>6;
  int v = s;
  #pragma unroll
  for(int d=1; d<64; d<<=1){
    int u = __shfl_up(v, d);
    if(lane >= d) v += u;
  }
  if(lane==63) wsum[wv] = v;
  __syncthreads();
  if(t==0){
    int run = 0;
    #pragma unroll
    for(int i=0;i<16;i++){ int c = wsum[i]; wsum[i] = run; run += c; }
  }
  __syncthreads();
  int run = wsum[wv] + (v - s);   // exclusive prefix of this thread's chunk
  for(int i=lo;i<hi;i++){
    int c = cnt_cur[i];
    offs[i] = run;
    cnt_cur[i] = run;
    run += c;
  }
  if(t==1023) offs[NNODES] = run;  // thread 1023's chunk is empty -> run == total == NEDGES
}

__global__ __launch_bounds__(256) void k_fill(const int* __restrict__ src,
                                              const int* __restrict__ edst,
                                              const int* __restrict__ species,
                                              int* __restrict__ cur,
                                              int* __restrict__ dsts,
                                              int* __restrict__ sps,
                                              int* __restrict__ pos){
  int e = blockIdx.x*256 + threadIdx.x;
  if(e >= NEDGES) return;
  int s = src[e];
  if((unsigned)s >= NNODES) s = 0;
  int p = atomicAdd(&cur[s], 1);
  if((unsigned)p >= NEDGES) p = 0;
  pos[e] = p;
  int dn = edst[e];
  if((unsigned)dn >= NNODES) dn = 0;
  dsts[p] = dn;
  int sp = species[dn];
  if((unsigned)sp >= 51) sp = 0;
  sps[p] = sp;
}

// ---------------- radial basis -> sorted bf16 rows g_s[p][16] ----------------
__global__ __launch_bounds__(256) void k_G(const void* __restrict__ dist,
                                           const void* __restrict__ sw,
                                           const int* __restrict__ modep,
                                           const int* __restrict__ pos,
                                           uint16_t* __restrict__ gs){
  int e = blockIdx.x*256 + threadIdx.x;
  if(e >= NEDGES) return;
  int md = *modep;
  float r = ldf(dist, e, md);
  float w = ldf(sw, e, md);
  float rinv = 1.0f/r;
  const float sigma = 0.8f/15.0f;
  const float isig  = 15.0f/0.8f;
  uint32_t u[8];
  #pragma unroll
  for(int j=0;j<8;j++){
    float mu0 = 0.2f + sigma*(float)(2*j);
    float mu1 = 0.2f + sigma*(float)(2*j+1);
    float t0 = (rinv-mu0)*isig, t1 = (rinv-mu1)*isig;
    u[j] = packbf(w*__expf(-0.5f*t0*t0), w*__expf(-0.5f*t1*t1));
  }
  int p = pos[e];
  uint4* o = (uint4*)(gs + (size_t)p*16);
  o[0] = make_uint4(u[0],u[1],u[2],u[3]);
  o[1] = make_uint4(u[4],u[5],u[6],u[7]);
}

// ---------------- species tables: ZWs0 fp32, zfb bf16 (51x16) ----------------
__global__ __launch_bounds__(128) void k_spec(const void* __restrict__ Z,
                                              const void* __restrict__ Ws0,
                                              const void* __restrict__ bs0,
                                              const int* __restrict__ modep,
                                              float* __restrict__ ZWs0,
                                              uint16_t* __restrict__ zfb){
  int s = blockIdx.x, d = threadIdx.x;
  int md = *modep;
  float zk[16];
  #pragma unroll
  for(int k=0;k<16;k++) zk[k] = ldf(Z, s*16+k, md);
  float a = ldf(bs0, d, md);
  #pragma unroll
  for(int k=0;k<16;k++) a = fmaf(zk[k], ldf(Ws0, k*128+d, md), a);
  ZWs0[s*128+d] = a;
  if(d < 16) zfb[s*16+d] = f2bf(zk[d]);
}

// ---------------- pack W (Kx128 fp32) into MFMA B-fragment layout, bf16 ----------------
__global__ __launch_bounds__(256) void k_prepB(const float* __restrict__ W, int Ksteps,
                                               uint16_t* __restrict__ Bf){
  int idx = blockIdx.x*256 + threadIdx.x;
  int total = Ksteps*8*64;
  if(idx >= total) return;
  int l = idx & 63, nt = (idx>>6)&7, kk = idx>>9;
  int kbase = kk*32 + (l>>4)*8;
  int dim = nt*16 + (l&15);
  uint32_t u[4];
  #pragma unroll
  for(int t=0;t<4;t++){
    float f0 = W[(size_t)(kbase+2*t)*128 + dim];
    float f1 = W[(size_t)(kbase+2*t+1)*128 + dim];
    u[t] = packbf(f0,f1);
  }
  ((uint4*)Bf)[idx] = make_uint4(u[0],u[1],u[2],u[3]);
}

// pack all 12 onsite 128x128 weights into frags
__global__ __launch_bounds__(256) void k_prepW(const float* __restrict__ conv,
                                               uint16_t* __restrict__ Wf){
  int idx = blockIdx.x*256 + threadIdx.x;
  if(idx >= 12*2048) return;
  int wi = idx>>11, r = idx&2047;
  int l = r & 63, nt = (r>>6)&7, kk = r>>9;
  const float* W = conv + ((wi<6) ? (OFF_WA + wi*16384) : (OFF_WB + (wi-6)*16384));
  int kbase = kk*32 + (l>>4)*8;
  int dim = nt*16 + (l&15);
  uint32_t u[4];
  #pragma unroll
  for(int t=0;t<4;t++){
    float f0 = W[(size_t)(kbase+2*t)*128 + dim];
    float f1 = W[(size_t)(kbase+2*t+1)*128 + dim];
    u[t] = packbf(f0,f1);
  }
  ((uint4*)Wf)[idx] = make_uint4(u[0],u[1],u[2],u[3]);
}

// ---------------- layer-0 fused: MFMA phase A (T0^T = Zf^T @ G) + MFMA GEMM ----------------
// block = 4 waves = one mtile (16 nodes). LDS: 8 ksteps x 64 slots x 8 bf16.
__global__ __launch_bounds__(256) void k_msg0f(const int* __restrict__ offs,
                                               const int* __restrict__ sps,
                                               const uint16_t* __restrict__ gs,
                                               const uint16_t* __restrict__ zfb,
                                               const uint16_t* __restrict__ Bf,
                                               const int* __restrict__ species,
                                               const float* __restrict__ ZWs0,
                                               float* __restrict__ zi){
  __shared__ uint16_t ldsA[8*64*8];   // 8 KB
  int w = threadIdx.x>>6, l = threadIdx.x&63;
  int n0 = blockIdx.x*16;
  int col = l&15, quad = l>>4;
  // phase A: 4 nodes per wave; T0^T[zk][b] = sum_e zfb[sp_e][zk] * g[e][b]
  for(int i=0;i<4;i++){
    int m = w*4 + i;
    int n = n0 + m;
    int beg = offs[n], end = offs[n+1];
    floatx4 acc0 = (floatx4){0.f,0.f,0.f,0.f};
    for(int p0=beg; p0<end; p0+=32){
      int sp[8];
      union { short8 s; uint16_t u[8]; } Bg, Az;
      #pragma unroll
      for(int j=0;j<8;j++){
        int p = p0 + quad*8 + j;
        int pc = p < end ? p : beg;
        sp[j] = sps[pc];
        uint16_t g = gs[(size_t)pc*16 + col];
        Bg.u[j] = (p < end) ? g : (uint16_t)0;
      }
      #pragma unroll
      for(int j=0;j<8;j++)
        Az.u[j] = zfb[sp[j]*16 + col];
      acc0 = __builtin_amdgcn_mfma_f32_16x16x32_bf16(Az.s, Bg.s, acc0, 0,0,0);
    }
    // value (zk = quad*4+reg, b = col): K = b*16 + zk
    int K0 = col*16 + quad*4;
    int kk = K0>>5, qt = (K0>>3)&3, jt = K0&7;
    int slot = kk*64 + ((qt*16 + m) ^ (kk>>2));
    uint32_t lo = packbf(acc0[0], acc0[1]);
    uint32_t hi = packbf(acc0[2], acc0[3]);
    *(uint2*)(&ldsA[slot*8 + jt]) = make_uint2(lo, hi);
  }
  __syncthreads();
  // phase B: wave w -> ntiles w and w+4
  floatx4 acc1 = (floatx4){0.f,0.f,0.f,0.f};
  floatx4 acc2 = (floatx4){0.f,0.f,0.f,0.f};
  const short8* Bp = (const short8*)Bf;
  int nt1 = w, nt2 = w+4;
  #pragma unroll
  for(int kk=0;kk<8;kk++){
    short8 a = *(const short8*)(&ldsA[(kk*64 + (l^(kk>>2)))*8]);
    short8 b1 = Bp[(size_t)(kk*8+nt1)*64 + l];
    short8 b2 = Bp[(size_t)(kk*8+nt2)*64 + l];
    acc1 = __builtin_amdgcn_mfma_f32_16x16x32_bf16(a, b1, acc1, 0,0,0);
    acc2 = __builtin_amdgcn_mfma_f32_16x16x32_bf16(a, b2, acc2, 0,0,0);
  }
  #pragma unroll
  for(int reg=0;reg<4;reg++){
    int node = n0 + quad*4 + reg;
    int sp = species[node];
    if((unsigned)sp >= 51) sp = 0;
    int d1 = nt1*16 + col, d2 = nt2*16 + col;
    zi[(size_t)node*128 + d1] = siluf(acc1[reg] + ZWs0[sp*128 + d1]);
    zi[(size_t)node*128 + d2] = siluf(acc2[reg] + ZWs0[sp*128 + d2]);
  }
}

// ---------------- layer-1 fused: MFMA phase A (T^T = Z^T @ G) + MFMA GEMM (KS1=68) ----------------
// block = 8 waves (512 thr) = one mtile. LDS: 64 ksteps x 64 slots x 8 bf16 = 64 KB.
// zib2 layout: [n][col*8+mt] (transposed) -> one b128 load per edge gives all 8 mt at this lane's col.
__global__ __launch_bounds__(512) void k_msg1f(const int* __restrict__ offs,
                                               const int* __restrict__ dsts,
                                               const uint16_t* __restrict__ gs,
                                               const uint16_t* __restrict__ zib,   // linear, ksteps 64..67
                                               const uint16_t* __restrict__ zib2,  // transposed, gathers
                                               const uint16_t* __restrict__ Bf,
                                               const float* __restrict__ bias,
                                               float* __restrict__ zacc){
  __shared__ uint16_t ldsA[64*64*8];   // 64 KB
  int w = threadIdx.x>>6, l = threadIdx.x&63;
  int n0 = blockIdx.x*16;
  int col = l&15, quad = l>>4;
  // phase A: 2 nodes per wave
  for(int i=0;i<2;i++){
    int m = w*2 + i;
    int n = n0 + m;
    int beg = offs[n], end = offs[n+1];
    floatx4 acc[8];
    #pragma unroll
    for(int t=0;t<8;t++) acc[t] = (floatx4){0.f,0.f,0.f,0.f};
    for(int p0=beg; p0<end; p0+=32){
      int dn[8];
      union { short8 s; uint16_t u[8]; } Bg;
      #pragma unroll
      for(int j=0;j<8;j++){
        int p = p0 + quad*8 + j;
        int pc = p < end ? p : beg;
        dn[j] = dsts[pc];
        uint16_t g = gs[(size_t)pc*16 + col];
        Bg.u[j] = (p < end) ? g : (uint16_t)0;
      }
      uint4 row[8];
      #pragma unroll
      for(int j=0;j<8;j++)
        row[j] = *(const uint4*)(zib2 + (size_t)dn[j]*128 + col*8);
      // transpose 8x8 bf16: Az[mt].u16[j] = row[j].u16[mt]  (v_perm)
      #pragma unroll
      for(int mt=0;mt<8;mt++){
        union { short8 s; uint32_t u32[4]; } Az;
        #pragma unroll
        for(int cp=0;cp<4;cp++){
          uint32_t a = ((const uint32_t*)&row[2*cp])[mt>>1];
          uint32_t b = ((const uint32_t*)&row[2*cp+1])[mt>>1];
          Az.u32[cp] = __builtin_amdgcn_perm(b, a, (mt&1) ? 0x07060302u : 0x05040100u);
        }
        acc[mt] = __builtin_amdgcn_mfma_f32_16x16x32_bf16(Az.s, Bg.s, acc[mt], 0,0,0);
      }
    }
    // value (kz = mt*16 + quad*4+reg, b = col): K = b*128 + kz; reg -> 4 consecutive K
    #pragma unroll
    for(int mt=0;mt<8;mt++){
      int K0 = col*128 + mt*16 + quad*4;
      int kk = K0>>5, qt = (K0>>3)&3, jt = K0&7;
      int slot = kk*64 + ((qt*16 + m) ^ (kk>>2));
      uint32_t lo = packbf(acc[mt][0], acc[mt][1]);
      uint32_t hi = packbf(acc[mt][2], acc[mt][3]);
      *(uint2*)(&ldsA[slot*8 + jt]) = make_uint2(lo, hi);
    }
  }
  __syncthreads();
  // phase B: wave w -> ntile w; ksteps 0..63 from LDS, 64..67 from zib (zself via Ws1 frags)
  floatx4 acc1 = (floatx4){0.f,0.f,0.f,0.f};
  const short8* Bp = (const short8*)Bf;
  for(int kk=0;kk<64;kk++){
    short8 a = *(const short8*)(&ldsA[(kk*64 + (l^(kk>>2)))*8]);
    short8 b1 = Bp[(size_t)(kk*8+w)*64 + l];
    acc1 = __builtin_amdgcn_mfma_f32_16x16x32_bf16(a, b1, acc1, 0,0,0);
  }
  #pragma unroll
  for(int kk=64;kk<KS1;kk++){
    uint4 za = *(const uint4*)(zib + (size_t)(n0+col)*128 + (kk-64)*32 + quad*8);
    union { short8 s; uint4 u; } A; A.u = za;
    short8 b1 = Bp[(size_t)(kk*8+w)*64 + l];
    acc1 = __builtin_amdgcn_mfma_f32_16x16x32_bf16(A.s, b1, acc1, 0,0,0);
  }
  #pragma unroll
  for(int reg=0;reg<4;reg++){
    int node = n0 + quad*4 + reg;
    int d1 = w*16 + col;
    zacc[(size_t)node*128 + d1] = siluf(acc1[reg] + bias[d1]);
  }
}

// ---------------- onsite via MFMA: 3 x (h=silu(z@Wa+ba); z+=h@Wb+bb) ----------------
// block = 256 thr = 4 waves = one mtile; each wave computes 2 n-tiles per GEMM stage.
__global__ __launch_bounds__(256) void k_onsite(float* __restrict__ zi,
                                                const uint16_t* __restrict__ Waf,
                                                const float* __restrict__ ba,
                                                const uint16_t* __restrict__ Wbf,
                                                const float* __restrict__ bb,
                                                void* __restrict__ outb,
                                                long off1, int st1,
                                                long off2, int st2,
                                                const int* __restrict__ modep,
                                                uint16_t* __restrict__ zib,
                                                uint16_t* __restrict__ zib2){
  __shared__ float zb[16*132];
  __shared__ float hb[16*132];
  int w = threadIdx.x>>6, l = threadIdx.x&63;
  int mtile = blockIdx.x;
  int n0 = mtile*16;
  int md = *modep;
  #pragma unroll
  for(int i=0;i<2;i++){
    int flat = (i*256 + threadIdx.x)*4;
    int node = flat>>7, k = flat&127;
    *(float4*)(zb + node*132 + k) = *(const float4*)(zi + (size_t)(n0+node)*128 + k);
  }
  __syncthreads();
  int m = l&15, q = l>>4;
  for(int j=0;j<3;j++){
    // stage 1: h = silu(z@Wa + ba); wave w -> ntiles 2w, 2w+1
    const short8* Ba = (const short8*)Waf + (size_t)j*2048 + l;
    floatx4 acc[2];
    acc[0] = (floatx4){0.f,0.f,0.f,0.f};
    acc[1] = (floatx4){0.f,0.f,0.f,0.f};
    #pragma unroll
    for(int kk=0;kk<4;kk++){
      const float* zp = zb + m*132 + kk*32 + q*8;
      float4 a0 = *(const float4*)zp, a1 = *(const float4*)(zp+4);
      union { short8 s; uint32_t u[4]; } A;
      A.u[0]=packbf(a0.x,a0.y); A.u[1]=packbf(a0.z,a0.w);
      A.u[2]=packbf(a1.x,a1.y); A.u[3]=packbf(a1.z,a1.w);
      #pragma unroll
      for(int t=0;t<2;t++){
        short8 bfr = Ba[(size_t)(kk*8 + w*2+t)*64];
        acc[t] = __builtin_amdgcn_mfma_f32_16x16x32_bf16(A.s, bfr, acc[t], 0,0,0);
      }
    }
    #pragma unroll
    for(int t=0;t<2;t++){
      int dim = (w*2+t)*16 + m;
      float bv = ba[j*128+dim];
      #pragma unroll
      for(int reg=0;reg<4;reg++)
        hb[(q*4+reg)*132 + dim] = siluf(acc[t][reg] + bv);
    }
    __syncthreads();
    // stage 2: z += h@Wb + bb; wave w -> ntiles 2w, 2w+1
    const short8* Bb = (const short8*)Wbf + (size_t)j*2048 + l;
    floatx4 acc2[2];
    acc2[0] = (floatx4){0.f,0.f,0.f,0.f};
    acc2[1] = (floatx4){0.f,0.f,0.f,0.f};
    #pragma unroll
    for(int kk=0;kk<4;kk++){
      const float* hp = hb + m*132 + kk*32 + q*8;
      float4 a0 = *(const float4*)hp, a1 = *(const float4*)(hp+4);
      union { short8 s; uint32_t u[4]; } A;
      A.u[0]=packbf(a0.x,a0.y); A.u[1]=packbf(a0.z,a0.w);
      A.u[2]=packbf(a1.x,a1.y); A.u[3]=packbf(a1.z,a1.w);
      #pragma unroll
      for(int t=0;t<2;t++){
        short8 bfr = Bb[(size_t)(kk*8 + w*2+t)*64];
        acc2[t] = __builtin_amdgcn_mfma_f32_16x16x32_bf16(A.s, bfr, acc2[t], 0,0,0);
      }
    }
    #pragma unroll
    for(int t=0;t<2;t++){
      int dim = (w*2+t)*16 + m;
      float bv = bb[j*128+dim];
      #pragma unroll
      for(int reg=0;reg<4;reg++){
        int idx = (q*4+reg)*132 + dim;
        zb[idx] = zb[idx] + acc2[t][reg] + bv;
      }
    }
    __syncthreads();
  }
  #pragma unroll
  for(int i=0;i<2;i++){
    int flat = (i*256 + threadIdx.x)*4;
    int node = flat>>7, k = flat&127;
    float4 v = *(float4*)(zb + node*132 + k);
    int n = n0 + node;
    *(float4*)(zi + (size_t)n*128 + k) = v;
    uint2 pv = make_uint2(packbf(v.x,v.y), packbf(v.z,v.w));
    if(zib) *(uint2*)(zib + (size_t)n*128 + k) = pv;
    if(md==1){
      uint16_t* ob = (uint16_t*)outb;
      *(uint2*)(ob + off1 + (long)n*st1 + k) = pv;
      if(off2 >= 0) *(uint2*)(ob + off2 + (long)n*st2 + k) = pv;
    } else {
      float* ob = (float*)outb;
      *(float4*)(ob + off1 + (long)n*st1 + k) = v;
      if(off2 >= 0) *(float4*)(ob + off2 + (long)n*st2 + k) = v;
    }
  }
  // transposed bf16 copy zib2[n][c*8+mt] = z[n][mt*16+c] (coalesced store, LDS-sourced)
  if(zib2){
    int node2 = threadIdx.x>>4, c = threadIdx.x&15;
    float vv[8];
    #pragma unroll
    for(int mt=0;mt<8;mt++) vv[mt] = zb[node2*132 + mt*16 + c];
    uint4 o = make_uint4(packbf(vv[0],vv[1]), packbf(vv[2],vv[3]),
                         packbf(vv[4],vv[5]), packbf(vv[6],vv[7]));
    *(uint4*)(zib2 + (size_t)(n0+node2)*128 + c*8) = o;
  }
}

extern "C" void kernel_launch(void* const* d_in, const int* in_sizes, int n_in,
                              void* d_out, int out_size, void* d_ws, size_t ws_size,
                              hipStream_t stream){
  const int* species = (const int*)d_in[0];
  const int* esrc    = (const int*)d_in[1];
  const int* edst    = (const int*)d_in[2];
  const void* dist   = d_in[3];
  const void* swit   = d_in[4];
  const void* Z      = d_in[5];
  const void* Ws0    = d_in[6];
  const void* bs0    = d_in[7];
  const void* V0     = d_in[8];
  const void* Ws1    = d_in[9];
  const void* bs1    = d_in[10];
  const void* V1     = d_in[11];
  const void* Wa     = d_in[12];
  const void* ba     = d_in[13];
  const void* Wb     = d_in[14];
  const void* bb     = d_in[15];

  char* ws = (char*)d_ws;
  size_t off = 0;
  auto alloc = [&](size_t bytes)->void*{ void* p = ws + off; off = (off + bytes + 255) & ~(size_t)255; return p; };
  int*      offs = (int*)     alloc((size_t)(NNODES+1)*4);
  int*      cur  = (int*)     alloc((size_t)NNODES*4);
  int*      pos  = (int*)     alloc((size_t)NEDGES*4);
  int*      dsts = (int*)     alloc((size_t)NEDGES*4);
  int*      sps  = (int*)     alloc((size_t)NEDGES*4);
  uint16_t* gs   = (uint16_t*)alloc((size_t)NEDGES*16*2);      // 12.8 MB
  float*    zi   = (float*)   alloc((size_t)NNODES*128*4);     // 10.24 MB
  float*    zacc = (float*)   alloc((size_t)NNODES*128*4);     // 10.24 MB
  uint16_t* zib  = (uint16_t*)alloc((size_t)NNODES*128*2);     // 5.12 MB
  uint16_t* zib2 = (uint16_t*)alloc((size_t)NNODES*128*2);     // 5.12 MB (transposed)
  float*    ZWs0 = (float*)   alloc((size_t)51*128*4);
  uint16_t* zfb  = (uint16_t*)alloc((size_t)51*16*2);
  float*    conv = (float*)   alloc((size_t)N_CONV*4);         // 2.04 MB
  uint16_t* Bf0  = (uint16_t*)alloc((size_t)8*8*64*8*2);       // 64 KB
  uint16_t* Bf1  = (uint16_t*)alloc((size_t)KS1*8*64*8*2);     // 557 KB
  uint16_t* Wfr  = (uint16_t*)alloc((size_t)12*16384*2);       // 384 KB
  int*      mode = (int*)     alloc(256);

  const int EB = (NEDGES+255)/256;
  hipMemsetAsync(cur, 0, NNODES*4, stream);
  k_probe<<<1,64,0,stream>>>(dist, mode);
  k_conv <<<(N_CONV+255)/256,256,0,stream>>>(V0, Ws1, bs1, V1, Wa, ba, Wb, bb, mode, conv);
  k_hist <<<EB,256,0,stream>>>(esrc, cur);
  k_scan <<<1,1024,0,stream>>>(cur, offs);
  k_fill <<<EB,256,0,stream>>>(esrc, edst, species, cur, dsts, sps, pos);
  k_G    <<<EB,256,0,stream>>>(dist, swit, mode, pos, gs);
  k_spec <<<51,128,0,stream>>>(Z, Ws0, bs0, mode, ZWs0, zfb);
  k_prepB<<<(8*8*64+255)/256,256,0,stream>>>(conv+OFF_V0, 8,  Bf0);
  k_prepB<<<(64*8*64+255)/256,256,0,stream>>>(conv+OFF_V1, 64, Bf1);
  k_prepB<<<(4*8*64+255)/256,256,0,stream>>>(conv+OFF_WS1, 4, Bf1 + (size_t)64*8*64*8);
  k_prepW<<<(12*2048+255)/256,256,0,stream>>>(conv, Wfr);

  const long ZIS = (long)NNODES*128;
  uint16_t* WaF0 = Wfr;
  uint16_t* WaF1 = Wfr + (size_t)3*16384;
  uint16_t* WbF0 = Wfr + (size_t)6*16384;
  uint16_t* WbF1 = Wfr + (size_t)9*16384;

  // layer 0 (fused MFMA scatter+GEMM)
  k_msg0f<<<MTILES,256,0,stream>>>(offs, sps, gs, zfb, Bf0, species, ZWs0, zi);
  k_onsite<<<MTILES,256,0,stream>>>(zi, WaF0, conv+OFF_BA, WbF0, conv+OFF_BB,
                                    d_out, ZIS, 256, (long)-1, 0, mode, zib, zib2);

  // layer 1 (fused MFMA scatter+GEMM incl. zself ksteps; gathers via transposed zib2)
  k_msg1f<<<MTILES,512,0,stream>>>(offs, dsts, gs, zib, zib2, Bf1, conv+OFF_BS1, zacc);
  k_onsite<<<MTILES,256,0,stream>>>(zacc, WaF1, conv+OFF_BA+384, WbF1, conv+OFF_BB+384,
                                    d_out, ZIS+128, 256, (long)0, 128, mode,
                                    (uint16_t*)nullptr, (uint16_t*)nullptr);
}